// Round 12
// baseline (348.228 us; speedup 1.0000x reference)
//
#include <hip/hip_runtime.h>

// Problem constants
#define NDRUG 50000
#define NDIS  50000
#define RR    5
#define FF    128
#define EFFD  128
#define OUTD  64
#define EE    400000
#define NCOL  (RR * OUTD)        // 320 columns in fused OUTPUT layout [n][r*64+o]
#define NB    (RR * NDIS)        // 250000 bins per direction
#define NEDGE (RR * EE)          // 2,000,000 edges per direction

// Two-level bucket sort
#define NBKT    196              // coarse buckets per (dir,r): dst>>8 (50000/256)
#define CAP     4096             // slot capacity per bucket (avg fill 2048, ~45 sigma headroom)
#define NGB     (2 * RR * NBKT)  // 1960 global buckets
#define QBKT    49               // buckets per dst-quarter (196 = 4*49)
#define STCAP   2048             // LDS staging entries per k_part block

// XCD partitioning for k_part: 8 partitions = dir(2) x dst-quarter(4)
#define NPART   8
#define NCHUNKE 64               // edge chunks per r
#define CHUNKE  (EE / NCHUNKE)   // 6250 edges per chunk

typedef unsigned short ushort_t;
typedef unsigned int uint_t;
typedef short short8 __attribute__((ext_vector_type(8)));
typedef float f32x4 __attribute__((ext_vector_type(4)));

// f32 -> bf16 round-to-nearest-even
static __device__ __forceinline__ ushort_t f2bf(float f) {
    uint_t u = __float_as_uint(f);
    uint_t r = (u + 0x7FFFu + ((u >> 16) & 1u)) >> 16;
    return (ushort_t)r;
}

// ---------------------------------------------------------------------------
// Kernel A: Mt[col][f] = bf16( sum_e (att[r,0]*basis[0,f,e]+att[r,1]*basis[1,f,e]) * fc_w[e,o] )
// ---------------------------------------------------------------------------
__global__ __launch_bounds__(256) void k_make_M(const float* __restrict__ att,
                                                const float* __restrict__ basis,
                                                const float* __restrict__ fcw,
                                                ushort_t* __restrict__ Mt) {
    int tid = blockIdx.x * 256 + threadIdx.x;
    if (tid >= RR * FF * OUTD) return;
    int r = tid / (FF * OUTD);
    int rem = tid - r * FF * OUTD;
    int f = rem >> 6;
    int o = rem & 63;
    float a0 = att[r * 2 + 0], a1 = att[r * 2 + 1];
    const float* b0 = basis + f * EFFD;
    const float* b1 = basis + FF * EFFD + f * EFFD;
    float acc = 0.f;
#pragma unroll 4
    for (int e = 0; e < EFFD; ++e) {
        float w = a0 * b0[e] + a1 * b1[e];
        acc += w * fcw[e * OUTD + o];
    }
    Mt[(size_t)(r * OUTD + o) * FF + f] = f2bf(acc);
}

// ---------------------------------------------------------------------------
// Kernel B (MFMA): g[r][n][o] = bf16( cj[n] * sum_k feat[n][k] * M[k][r*64+o] )
// RATING-MAJOR g layout: per-(dir,r) gather region is a dense 6.4 MB block
// -> k_agg's random gathers become L2/L3-resident instead of HBM-random.
// ---------------------------------------------------------------------------
__global__ __launch_bounds__(256) void k_gemm(const float* __restrict__ featA,
                                              const float* __restrict__ cjA,
                                              const float* __restrict__ featB,
                                              const float* __restrict__ cjB,
                                              const ushort_t* __restrict__ Mt,
                                              ushort_t* __restrict__ gA,
                                              ushort_t* __restrict__ gB) {
    const float* feat; const float* cj; ushort_t* g;
    if (blockIdx.z == 0) { feat = featA; cj = cjA; g = gA; }
    else                 { feat = featB; cj = cjB; g = gB; }

    __shared__ ushort_t featS[64][136];
    __shared__ ushort_t mtS[160][136];

    const int tid  = threadIdx.x;
    const int row0 = blockIdx.x * 64;
    const int ch0  = blockIdx.y * 160;

    for (int i = tid; i < 64 * 32; i += 256) {
        int r  = i >> 5;
        int c4 = (i & 31) << 2;
        float4 v = make_float4(0.f, 0.f, 0.f, 0.f);
        int row = row0 + r;
        if (row < NDRUG) v = *(const float4*)(feat + (size_t)row * FF + c4);
        ushort4 pk;
        pk.x = f2bf(v.x); pk.y = f2bf(v.y); pk.z = f2bf(v.z); pk.w = f2bf(v.w);
        *(ushort4*)&featS[r][c4] = pk;
    }
    for (int i = tid; i < 160 * 16; i += 256) {
        int c  = i >> 4;
        int q8 = (i & 15) << 3;
        *(short8*)&mtS[c][q8] = *(const short8*)(Mt + (size_t)(ch0 + c) * FF + q8);
    }
    __syncthreads();

    const int w = tid >> 6;
    const int l = tid & 63;
    const int lr = l & 15;
    const int lg = l >> 4;

    short8 afrag[4];
#pragma unroll
    for (int ks = 0; ks < 4; ++ks)
        afrag[ks] = *(const short8*)&featS[w * 16 + lr][ks * 32 + lg * 8];

    const int rbase = row0 + w * 16 + (lg << 2);
    float cjv[4];
#pragma unroll
    for (int rg = 0; rg < 4; ++rg)
        cjv[rg] = (rbase + rg < NDRUG) ? cj[rbase + rg] : 0.f;

#pragma unroll
    for (int n = 0; n < 10; ++n) {
        f32x4 c = {0.f, 0.f, 0.f, 0.f};
#pragma unroll
        for (int ks = 0; ks < 4; ++ks) {
            short8 b = *(const short8*)&mtS[n * 16 + lr][ks * 32 + lg * 8];
            c = __builtin_amdgcn_mfma_f32_16x16x32_bf16(afrag[ks], b, c, 0, 0, 0);
        }
        int col = ch0 + n * 16 + lr;
        int rr  = col >> 6;          // rating
        int oo  = col & 63;          // output col within rating
#pragma unroll
        for (int rg = 0; rg < 4; ++rg) {
            int row = rbase + rg;
            if (row < NDRUG)
                g[((size_t)rr * NDRUG + row) * OUTD + oo] = f2bf(c[rg] * cjv[rg]);
        }
    }
}

// ---------------------------------------------------------------------------
// Pass 1: coarse partition with block-local aggregation.
// Entry: ((dst&255)<<16 | src) into slotted bucket (dir, r, dst>>8).
// ---------------------------------------------------------------------------
__global__ __launch_bounds__(256) void k_part(const int* __restrict__ ed,
                                              const int* __restrict__ ei,
                                              int* __restrict__ tails,
                                              uint_t* __restrict__ coarse) {
    int p = blockIdx.x & (NPART - 1);
    int dir = p >> 2;
    int quarter = p & 3;
    int chunk = blockIdx.x >> 3;
    int r = blockIdx.y;
    const int* dstarr = (dir ? ed : ei) + (size_t)r * EE;
    const int* srcarr = (dir ? ei : ed) + (size_t)r * EE;
    int* tl = tails + (dir * RR + r) * NBKT;
    uint_t* cb = coarse + (size_t)(dir * RR + r) * NBKT * CAP;
    int blo = quarter * QBKT;

    __shared__ uint_t stage[STCAP];
    __shared__ int cnt[QBKT];
    __shared__ int cur[QBKT];
    __shared__ int gpos[QBKT];
    __shared__ int nstage;

    int t = threadIdx.x;
    if (t < QBKT) { cnt[t] = 0; cur[t] = 0; }
    if (t == 0) nstage = 0;
    __syncthreads();

    int lane = t & 63;
    int e0 = chunk * CHUNKE;
    for (int i = e0 + t; i < e0 + CHUNKE; i += 256) {
        int d = __builtin_nontemporal_load(dstarr + i);
        int b = (d >> 8) - blo;
        bool m = ((unsigned)b < (unsigned)QBKT);
        unsigned long long mask = __ballot(m);
        if (mask) {
            int src = m ? __builtin_nontemporal_load(srcarr + i) : 0;
            int nw = __popcll(mask);
            int prefix = __popcll(mask & ((1ull << lane) - 1ull));
            int leader = (int)__ffsll((unsigned long long)mask) - 1;
            int wbase = 0;
            if (lane == leader) wbase = atomicAdd(&nstage, nw);
            wbase = __shfl(wbase, leader);
            if (m) {
                int idx = wbase + prefix;
                if (idx < STCAP) {
                    stage[idx] = ((uint_t)b << 26) | ((uint_t)(d & 255) << 16)
                               | (uint_t)(ushort_t)src;
                    atomicAdd(&cnt[b], 1);
                }
            }
        }
    }
    __syncthreads();

    if (t < QBKT) gpos[t] = atomicAdd(&tl[blo + t], cnt[t]);
    __syncthreads();

    int n = nstage; if (n > STCAP) n = STCAP;
    for (int i = t; i < n; i += 256) {
        uint_t e = stage[i];
        int b = e >> 26;
        int q = atomicAdd(&cur[b], 1);
        int idx = gpos[b] + q;
        if (idx < CAP)
            cb[(size_t)(blo + b) * CAP + idx] = e & 0x00FFFFFFu;
    }
}

// ---------------------------------------------------------------------------
// Pass 2: fine counting sort within each bucket (one block per bucket).
// grid: (NBKT, RR, 2)
// ---------------------------------------------------------------------------
__global__ __launch_bounds__(256) void k_fine(const uint_t* __restrict__ coarse,
                                              const int* __restrict__ tails,
                                              ushort_t* __restrict__ sorted,
                                              int* __restrict__ bins) {
    int b = blockIdx.x, r = blockIdx.y, dir = blockIdx.z;
    int gb = (dir * RR + r) * NBKT + b;
    size_t base = (size_t)gb * CAP;
    int count = tails[gb]; if (count > CAP) count = CAP;
    int t = threadIdx.x;

    __shared__ int cnt[256];
    __shared__ int incl[256];
    __shared__ int cur[256];

    cnt[t] = 0;
    __syncthreads();
    for (int i = t; i < count; i += 256)
        atomicAdd(&cnt[coarse[base + i] >> 16], 1);
    __syncthreads();

    int v = cnt[t];
    incl[t] = v;
    __syncthreads();
    for (int off = 1; off < 256; off <<= 1) {
        int x = (t >= off) ? incl[t - off] : 0;
        __syncthreads();
        incl[t] += x;
        __syncthreads();
    }
    int excl = incl[t] - v;
    cur[t] = excl;

    int d = b * 256 + t;
    if (d < NDIS)
        bins[dir * NB + r * NDIS + d] = (int)base + incl[t];   // absolute inclusive end
    __syncthreads();

    for (int i = t; i < count; i += 256) {
        uint_t e = coarse[base + i];
        int p = atomicAdd(&cur[e >> 16], 1);
        sorted[base + p] = (ushort_t)e;
    }
}

// ---------------------------------------------------------------------------
// Gather aggregation + fused epilogue. One wave per (dst, r) bin.
// 2 cols/lane (uint = 2 bf16), 2 edges per wave instruction; gathers hit the
// dense 6.4MB per-(dir,r) g region (rating-major layout) -> cache-resident.
// ---------------------------------------------------------------------------
__global__ __launch_bounds__(256) void k_agg(const ushort_t* __restrict__ gd,
                                             const ushort_t* __restrict__ gi,
                                             const int* __restrict__ bins,
                                             const ushort_t* __restrict__ sorted,
                                             const float* __restrict__ ci_drug,
                                             const float* __restrict__ ci_dis,
                                             const float* __restrict__ fcb,
                                             float* __restrict__ out_drug,
                                             float* __restrict__ out_dis) {
    int dir = blockIdx.y;
    const ushort_t* g   = dir ? gi : gd;
    const float* ci     = dir ? ci_drug : ci_dis;
    float* outp         = dir ? out_drug : out_dis;
    const int* bn       = bins + dir * NB;
    const ushort_t* srt = sorted;

    int wave = blockIdx.x * 4 + (threadIdx.x >> 6);
    int lane = threadIdx.x & 63;
    if (wave >= NB) return;
    int r = wave / NDIS;
    int dst = wave - r * NDIS;
    int gb = (dir * RR + r) * NBKT + (dst >> 8);
    int start = (dst & 255) ? bn[wave - 1] : gb * CAP;
    int end = bn[wave];

    const int half = lane >> 5;            // which edge of the pair
    const int q    = lane & 31;            // uint index: cols 2q, 2q+1
    const ushort_t* grow = g + (size_t)r * NDRUG * OUTD + q * 2;

    float a0 = 0.f, a1 = 0.f;
    for (int base = start; base < end; base += 64) {
        int m = end - base; if (m > 64) m = 64;
        int li = lane < m ? lane : m - 1;
        int my = (int)srt[(size_t)base + li];
        for (int j = 0; j < m; j += 8) {
            uint_t u[4];
#pragma unroll
            for (int k = 0; k < 4; ++k) {
                int jj = j + 2 * k + half;
                int cl = jj < m ? jj : m - 1;
                int sj = __shfl(my, cl);
                u[k] = *(const uint_t*)(grow + (size_t)sj * OUTD);
            }
#pragma unroll
            for (int k = 0; k < 4; ++k) {
                int jj = j + 2 * k + half;
                uint_t um = jj < m ? u[k] : 0u;
                a0 += __uint_as_float(um << 16);
                a1 += __uint_as_float(um & 0xffff0000u);
            }
        }
    }
    a0 += __shfl_xor(a0, 32);
    a1 += __shfl_xor(a1, 32);
    if (half == 0) {
        float civ = ci[dst];
        float2 bb = *(const float2*)(fcb + q * 2);
        float2 v;
        v.x = a0 * civ + bb.x;
        v.y = a1 * civ + bb.y;
        *(float2*)(outp + (size_t)dst * NCOL + r * OUTD + q * 2) = v;
    }
}

// ---------------------------------------------------------------------------
extern "C" void kernel_launch(void* const* d_in, const int* in_sizes, int n_in,
                              void* d_out, int out_size, void* d_ws, size_t ws_size,
                              hipStream_t stream) {
    const float* drug_feat = (const float*)d_in[0];
    const float* dis_feat  = (const float*)d_in[1];
    const float* cj_drug   = (const float*)d_in[2];
    const float* ci_drug   = (const float*)d_in[3];
    const float* cj_dis    = (const float*)d_in[4];
    const float* ci_dis    = (const float*)d_in[5];
    const float* att       = (const float*)d_in[6];
    const float* basis     = (const float*)d_in[7];
    const float* fcw       = (const float*)d_in[8];
    const float* fcb       = (const float*)d_in[9];
    const int*   edge_drug = (const int*)d_in[10];
    const int*   edge_dis  = (const int*)d_in[11];

    float* out      = (float*)d_out;
    float* out_drug = out;
    float* out_dis  = out + (size_t)NDRUG * NCOL;

    // Workspace layout (~114.4 MB):
    //   gd (bf16, [R][N][64])   32,000,000 @ 0
    //   gi (bf16, [R][N][64])   32,000,000 @ 32,000,000
    //   Mt (bf16)      163,840 @ 64,000,000
    //   bins (int)   2,000,000 @ 64,200,000
    //   tails (int)      7,840 @ 66,200,000
    //   coarse (u32) 32,112,640 @ 66,208,000
    //   sorted (u16) 16,056,320 @ 98,320,640
    char* ws = (char*)d_ws;
    ushort_t* gd      = (ushort_t*)ws;
    ushort_t* gi      = (ushort_t*)(ws + 32000000);
    ushort_t* Mtb     = (ushort_t*)(ws + 64000000);
    int*      bins    = (int*)(ws + 64200000);
    int*      tails   = (int*)(ws + 66200000);
    uint_t*   coarse  = (uint_t*)(ws + 66208000);
    ushort_t* sorted  = (ushort_t*)(ws + 98320640);

    // zero bucket tails
    hipMemsetAsync(tails, 0, NGB * sizeof(int), stream);

    // A: fused att*basis*fc_w -> Mt bf16 [320][128]
    k_make_M<<<dim3((RR * FF * OUTD + 255) / 256), 256, 0, stream>>>(att, basis, fcw, Mtb);

    // B: g = bf16((feat @ M) * cj), both sides (MFMA), rating-major layout
    dim3 ggrid((NDRUG + 63) / 64, 2, 2);
    k_gemm<<<ggrid, 256, 0, stream>>>(drug_feat, cj_drug, dis_feat, cj_dis, Mtb, gd, gi);

    // Two-level bucket sort (dense writes, block-aggregated reservations)
    k_part<<<dim3(NCHUNKE * NPART, RR), 256, 0, stream>>>(edge_drug, edge_dis, tails, coarse);
    k_fine<<<dim3(NBKT, RR, 2), 256, 0, stream>>>(coarse, tails, sorted, bins);

    // Gather aggregation + fused ci-scale + bias
    k_agg<<<dim3((NB + 3) / 4, 2), 256, 0, stream>>>(gd, gi, bins, sorted,
                                                     ci_drug, ci_dis, fcb,
                                                     out_drug, out_dis);
}

// Round 13
// 303.320 us; speedup vs baseline: 1.1481x; 1.1481x over previous
//
#include <hip/hip_runtime.h>

// Problem constants
#define NDRUG 50000
#define NDIS  50000
#define RR    5
#define FF    128
#define EFFD  128
#define OUTD  64
#define EE    400000
#define NCOL  (RR * OUTD)        // 320 columns in fused OUTPUT layout [n][r*64+o]
#define NB    (RR * NDIS)        // 250000 bins per direction
#define NEDGE (RR * EE)          // 2,000,000 edges per direction

// Two-level bucket sort
#define NBKT    196              // coarse buckets per (dir,r): dst>>8 (50000/256)
#define CAP     4096             // slot capacity per bucket (avg fill 2048, ~45 sigma headroom)
#define NGB     (2 * RR * NBKT)  // 1960 global buckets

#define NCHUNKE 64               // edge chunks per (r,dir)
#define CHUNKE  (EE / NCHUNKE)   // 6250 edges per chunk (exact LDS stage fit)

typedef unsigned short ushort_t;
typedef unsigned int uint_t;
typedef short short8 __attribute__((ext_vector_type(8)));
typedef float f32x4 __attribute__((ext_vector_type(4)));

// f32 -> bf16 round-to-nearest-even
static __device__ __forceinline__ ushort_t f2bf(float f) {
    uint_t u = __float_as_uint(f);
    uint_t r = (u + 0x7FFFu + ((u >> 16) & 1u)) >> 16;
    return (ushort_t)r;
}

// ---------------------------------------------------------------------------
// Kernel A: Mt[col][f] = bf16( sum_e (att[r,0]*basis[0,f,e]+att[r,1]*basis[1,f,e]) * fc_w[e,o] )
// ---------------------------------------------------------------------------
__global__ __launch_bounds__(256) void k_make_M(const float* __restrict__ att,
                                                const float* __restrict__ basis,
                                                const float* __restrict__ fcw,
                                                ushort_t* __restrict__ Mt) {
    int tid = blockIdx.x * 256 + threadIdx.x;
    if (tid >= RR * FF * OUTD) return;
    int r = tid / (FF * OUTD);
    int rem = tid - r * FF * OUTD;
    int f = rem >> 6;
    int o = rem & 63;
    float a0 = att[r * 2 + 0], a1 = att[r * 2 + 1];
    const float* b0 = basis + f * EFFD;
    const float* b1 = basis + FF * EFFD + f * EFFD;
    float acc = 0.f;
#pragma unroll 4
    for (int e = 0; e < EFFD; ++e) {
        float w = a0 * b0[e] + a1 * b1[e];
        acc += w * fcw[e * OUTD + o];
    }
    Mt[(size_t)(r * OUTD + o) * FF + f] = f2bf(acc);
}

// ---------------------------------------------------------------------------
// Kernel B (MFMA): g[r][n][o] = bf16( cj[n] * sum_k feat[n][k] * M[k][r*64+o] )
// ---------------------------------------------------------------------------
__global__ __launch_bounds__(256) void k_gemm(const float* __restrict__ featA,
                                              const float* __restrict__ cjA,
                                              const float* __restrict__ featB,
                                              const float* __restrict__ cjB,
                                              const ushort_t* __restrict__ Mt,
                                              ushort_t* __restrict__ gA,
                                              ushort_t* __restrict__ gB) {
    const float* feat; const float* cj; ushort_t* g;
    if (blockIdx.z == 0) { feat = featA; cj = cjA; g = gA; }
    else                 { feat = featB; cj = cjB; g = gB; }

    __shared__ ushort_t featS[64][136];
    __shared__ ushort_t mtS[160][136];

    const int tid  = threadIdx.x;
    const int row0 = blockIdx.x * 64;
    const int ch0  = blockIdx.y * 160;

    for (int i = tid; i < 64 * 32; i += 256) {
        int r  = i >> 5;
        int c4 = (i & 31) << 2;
        float4 v = make_float4(0.f, 0.f, 0.f, 0.f);
        int row = row0 + r;
        if (row < NDRUG) v = *(const float4*)(feat + (size_t)row * FF + c4);
        ushort4 pk;
        pk.x = f2bf(v.x); pk.y = f2bf(v.y); pk.z = f2bf(v.z); pk.w = f2bf(v.w);
        *(ushort4*)&featS[r][c4] = pk;
    }
    for (int i = tid; i < 160 * 16; i += 256) {
        int c  = i >> 4;
        int q8 = (i & 15) << 3;
        *(short8*)&mtS[c][q8] = *(const short8*)(Mt + (size_t)(ch0 + c) * FF + q8);
    }
    __syncthreads();

    const int w = tid >> 6;
    const int l = tid & 63;
    const int lr = l & 15;
    const int lg = l >> 4;

    short8 afrag[4];
#pragma unroll
    for (int ks = 0; ks < 4; ++ks)
        afrag[ks] = *(const short8*)&featS[w * 16 + lr][ks * 32 + lg * 8];

    const int rbase = row0 + w * 16 + (lg << 2);
    float cjv[4];
#pragma unroll
    for (int rg = 0; rg < 4; ++rg)
        cjv[rg] = (rbase + rg < NDRUG) ? cj[rbase + rg] : 0.f;

#pragma unroll
    for (int n = 0; n < 10; ++n) {
        f32x4 c = {0.f, 0.f, 0.f, 0.f};
#pragma unroll
        for (int ks = 0; ks < 4; ++ks) {
            short8 b = *(const short8*)&mtS[n * 16 + lr][ks * 32 + lg * 8];
            c = __builtin_amdgcn_mfma_f32_16x16x32_bf16(afrag[ks], b, c, 0, 0, 0);
        }
        int col = ch0 + n * 16 + lr;
        int rr  = col >> 6;          // rating
        int oo  = col & 63;          // output col within rating
#pragma unroll
        for (int rg = 0; rg < 4; ++rg) {
            int row = rbase + rg;
            if (row < NDRUG)
                g[((size_t)rr * NDRUG + row) * OUTD + oo] = f2bf(c[rg] * cjv[rg]);
        }
    }
}

// ---------------------------------------------------------------------------
// Pass 1: coarse partition, dir-only split. Every edge in the chunk matches,
// so staging is deterministic (stage[i] = entry of edge e0+i), each edge
// array is read once per role (~2x total vs 8x with dst-quarters).
// One global atomicAdd per (block,bucket) reserves a contiguous run (~32
// entries = 128B) -> dense writes preserved. grid: (NCHUNKE*2, RR).
// ---------------------------------------------------------------------------
__global__ __launch_bounds__(256) void k_part(const int* __restrict__ ed,
                                              const int* __restrict__ ei,
                                              int* __restrict__ tails,
                                              uint_t* __restrict__ coarse) {
    int dir = blockIdx.x & 1;
    int chunk = blockIdx.x >> 1;
    int r = blockIdx.y;
    const int* dstarr = (dir ? ed : ei) + (size_t)r * EE;
    const int* srcarr = (dir ? ei : ed) + (size_t)r * EE;
    int* tl = tails + (dir * RR + r) * NBKT;
    uint_t* cb = coarse + (size_t)(dir * RR + r) * NBKT * CAP;

    __shared__ uint_t stage[CHUNKE];   // 25 KB
    __shared__ int cnt[NBKT];
    __shared__ int cur[NBKT];
    __shared__ int gpos[NBKT];

    int t = threadIdx.x;
    if (t < NBKT) { cnt[t] = 0; cur[t] = 0; }
    __syncthreads();

    int e0 = chunk * CHUNKE;
    for (int i = t; i < CHUNKE; i += 256) {
        int d = __builtin_nontemporal_load(dstarr + e0 + i);
        int s = __builtin_nontemporal_load(srcarr + e0 + i);
        int b = d >> 8;
        stage[i] = ((uint_t)b << 24) | ((uint_t)(d & 255) << 16) | (uint_t)(ushort_t)s;
        atomicAdd(&cnt[b], 1);
    }
    __syncthreads();

    if (t < NBKT) gpos[t] = atomicAdd(&tl[t], cnt[t]);
    __syncthreads();

    for (int i = t; i < CHUNKE; i += 256) {
        uint_t e = stage[i];
        int b = e >> 24;
        int q = atomicAdd(&cur[b], 1);
        int idx = gpos[b] + q;
        if (idx < CAP)
            cb[(size_t)b * CAP + idx] = e & 0x00FFFFFFu;
    }
}

// ---------------------------------------------------------------------------
// Pass 2: fine counting sort within each bucket (one block per bucket).
// grid: (NBKT, RR, 2)
// ---------------------------------------------------------------------------
__global__ __launch_bounds__(256) void k_fine(const uint_t* __restrict__ coarse,
                                              const int* __restrict__ tails,
                                              ushort_t* __restrict__ sorted,
                                              int* __restrict__ bins) {
    int b = blockIdx.x, r = blockIdx.y, dir = blockIdx.z;
    int gb = (dir * RR + r) * NBKT + b;
    size_t base = (size_t)gb * CAP;
    int count = tails[gb]; if (count > CAP) count = CAP;
    int t = threadIdx.x;

    __shared__ int cnt[256];
    __shared__ int incl[256];
    __shared__ int cur[256];

    cnt[t] = 0;
    __syncthreads();
    for (int i = t; i < count; i += 256)
        atomicAdd(&cnt[coarse[base + i] >> 16], 1);
    __syncthreads();

    int v = cnt[t];
    incl[t] = v;
    __syncthreads();
    for (int off = 1; off < 256; off <<= 1) {
        int x = (t >= off) ? incl[t - off] : 0;
        __syncthreads();
        incl[t] += x;
        __syncthreads();
    }
    int excl = incl[t] - v;
    cur[t] = excl;

    int d = b * 256 + t;
    if (d < NDIS)
        bins[dir * NB + r * NDIS + d] = (int)base + incl[t];   // absolute inclusive end
    __syncthreads();

    for (int i = t; i < count; i += 256) {
        uint_t e = coarse[base + i];
        int p = atomicAdd(&cur[e >> 16], 1);
        sorted[base + p] = (ushort_t)e;
    }
}

// ---------------------------------------------------------------------------
// Gather aggregation + fused epilogue. One wave per (dst, r) bin.
// 4 cols/lane (uint2 = 4 bf16), 16 lanes/edge, 8 edges per unrolled group:
// half the vmem instrs, 4x unpack amortization -> ~3.5 wave-instr/edge.
// Quarter-reduce via shfl_xor(16,32); 16 lanes write float4 with ci+bias.
// ---------------------------------------------------------------------------
__global__ __launch_bounds__(256) void k_agg(const ushort_t* __restrict__ gd,
                                             const ushort_t* __restrict__ gi,
                                             const int* __restrict__ bins,
                                             const ushort_t* __restrict__ sorted,
                                             const float* __restrict__ ci_drug,
                                             const float* __restrict__ ci_dis,
                                             const float* __restrict__ fcb,
                                             float* __restrict__ out_drug,
                                             float* __restrict__ out_dis) {
    int dir = blockIdx.y;
    const ushort_t* g   = dir ? gi : gd;
    const float* ci     = dir ? ci_drug : ci_dis;
    float* outp         = dir ? out_drug : out_dis;
    const int* bn       = bins + dir * NB;
    const ushort_t* srt = sorted;

    int wave = blockIdx.x * 4 + (threadIdx.x >> 6);
    int lane = threadIdx.x & 63;
    if (wave >= NB) return;
    int r = wave / NDIS;
    int dst = wave - r * NDIS;
    int gb = (dir * RR + r) * NBKT + (dst >> 8);
    int start = (dst & 255) ? bn[wave - 1] : gb * CAP;
    int end = bn[wave];

    const int quarter = lane >> 4;          // edge slot within group of 4
    const int q       = lane & 15;          // uint2 index: cols 4q..4q+3
    const ushort_t* grow = g + (size_t)r * NDRUG * OUTD + q * 4;

    float a0 = 0.f, a1 = 0.f, a2 = 0.f, a3 = 0.f;
    for (int base = start; base < end; base += 64) {
        int m = end - base; if (m > 64) m = 64;
        int li = lane < m ? lane : m - 1;
        int my = (int)srt[(size_t)base + li];
        for (int j = 0; j < m; j += 8) {
            uint2 u[2];
#pragma unroll
            for (int k = 0; k < 2; ++k) {
                int jj = j + 4 * k + quarter;
                int cl = jj < m ? jj : m - 1;
                int sj = __shfl(my, cl);
                u[k] = *(const uint2*)(grow + (size_t)sj * OUTD);
            }
#pragma unroll
            for (int k = 0; k < 2; ++k) {
                int jj = j + 4 * k + quarter;
                uint_t ux = jj < m ? u[k].x : 0u;
                uint_t uy = jj < m ? u[k].y : 0u;
                a0 += __uint_as_float(ux << 16);
                a1 += __uint_as_float(ux & 0xffff0000u);
                a2 += __uint_as_float(uy << 16);
                a3 += __uint_as_float(uy & 0xffff0000u);
            }
        }
    }
    a0 += __shfl_xor(a0, 16); a1 += __shfl_xor(a1, 16);
    a2 += __shfl_xor(a2, 16); a3 += __shfl_xor(a3, 16);
    a0 += __shfl_xor(a0, 32); a1 += __shfl_xor(a1, 32);
    a2 += __shfl_xor(a2, 32); a3 += __shfl_xor(a3, 32);
    if (quarter == 0) {
        float civ = ci[dst];
        float4 bb = *(const float4*)(fcb + q * 4);
        float4 v;
        v.x = a0 * civ + bb.x;
        v.y = a1 * civ + bb.y;
        v.z = a2 * civ + bb.z;
        v.w = a3 * civ + bb.w;
        *(float4*)(outp + (size_t)dst * NCOL + r * OUTD + q * 4) = v;
    }
}

// ---------------------------------------------------------------------------
extern "C" void kernel_launch(void* const* d_in, const int* in_sizes, int n_in,
                              void* d_out, int out_size, void* d_ws, size_t ws_size,
                              hipStream_t stream) {
    const float* drug_feat = (const float*)d_in[0];
    const float* dis_feat  = (const float*)d_in[1];
    const float* cj_drug   = (const float*)d_in[2];
    const float* ci_drug   = (const float*)d_in[3];
    const float* cj_dis    = (const float*)d_in[4];
    const float* ci_dis    = (const float*)d_in[5];
    const float* att       = (const float*)d_in[6];
    const float* basis     = (const float*)d_in[7];
    const float* fcw       = (const float*)d_in[8];
    const float* fcb       = (const float*)d_in[9];
    const int*   edge_drug = (const int*)d_in[10];
    const int*   edge_dis  = (const int*)d_in[11];

    float* out      = (float*)d_out;
    float* out_drug = out;
    float* out_dis  = out + (size_t)NDRUG * NCOL;

    // Workspace layout (~114.4 MB):
    //   gd (bf16, [R][N][64])   32,000,000 @ 0
    //   gi (bf16, [R][N][64])   32,000,000 @ 32,000,000
    //   Mt (bf16)      163,840 @ 64,000,000
    //   bins (int)   2,000,000 @ 64,200,000
    //   tails (int)      7,840 @ 66,200,000
    //   coarse (u32) 32,112,640 @ 66,208,000
    //   sorted (u16) 16,056,320 @ 98,320,640
    char* ws = (char*)d_ws;
    ushort_t* gd      = (ushort_t*)ws;
    ushort_t* gi      = (ushort_t*)(ws + 32000000);
    ushort_t* Mtb     = (ushort_t*)(ws + 64000000);
    int*      bins    = (int*)(ws + 64200000);
    int*      tails   = (int*)(ws + 66200000);
    uint_t*   coarse  = (uint_t*)(ws + 66208000);
    ushort_t* sorted  = (ushort_t*)(ws + 98320640);

    // zero bucket tails
    hipMemsetAsync(tails, 0, NGB * sizeof(int), stream);

    // A: fused att*basis*fc_w -> Mt bf16 [320][128]
    k_make_M<<<dim3((RR * FF * OUTD + 255) / 256), 256, 0, stream>>>(att, basis, fcw, Mtb);

    // B: g = bf16((feat @ M) * cj), both sides (MFMA), rating-major layout
    dim3 ggrid((NDRUG + 63) / 64, 2, 2);
    k_gemm<<<ggrid, 256, 0, stream>>>(drug_feat, cj_drug, dis_feat, cj_dis, Mtb, gd, gi);

    // Two-level bucket sort (dense writes, block-aggregated reservations)
    k_part<<<dim3(NCHUNKE * 2, RR), 256, 0, stream>>>(edge_drug, edge_dis, tails, coarse);
    k_fine<<<dim3(NBKT, RR, 2), 256, 0, stream>>>(coarse, tails, sorted, bins);

    // Gather aggregation + fused ci-scale + bias (4 cols/lane, 4 edges/instr)
    k_agg<<<dim3((NB + 3) / 4, 2), 256, 0, stream>>>(gd, gi, bins, sorted,
                                                     ci_drug, ci_dis, fcb,
                                                     out_drug, out_dis);
}

// Round 14
// 236.648 us; speedup vs baseline: 1.4715x; 1.2817x over previous
//
#include <hip/hip_runtime.h>

// Problem constants
#define NDRUG 50000
#define NDIS  50000
#define RR    5
#define FF    128
#define EFFD  128
#define OUTD  64
#define EE    400000
#define NCOL  (RR * OUTD)        // 320 columns in fused OUTPUT layout [n][r*64+o]
#define NEDGE (RR * EE)          // 2,000,000 edges per direction

// Two-level bucket sort
#define NBKT    196              // coarse buckets per (dir,r): dst>>8 (50000/256)
#define CAP     4096             // slot capacity per bucket (avg fill 2048, ~45 sigma headroom)
#define NGB     (2 * RR * NBKT)  // 1960 global buckets

#define NCHUNKE 64               // edge chunks per (r,dir)
#define CHUNKE  (EE / NCHUNKE)   // 6250 edges per chunk (exact LDS stage fit)

typedef unsigned short ushort_t;
typedef unsigned int uint_t;
typedef short short8 __attribute__((ext_vector_type(8)));
typedef float f32x4 __attribute__((ext_vector_type(4)));

// f32 -> bf16 round-to-nearest-even
static __device__ __forceinline__ ushort_t f2bf(float f) {
    uint_t u = __float_as_uint(f);
    uint_t r = (u + 0x7FFFu + ((u >> 16) & 1u)) >> 16;
    return (ushort_t)r;
}

// ---------------------------------------------------------------------------
// Kernel A: Mt[col][f] = bf16( sum_e (att[r,0]*basis[0,f,e]+att[r,1]*basis[1,f,e]) * fc_w[e,o] )
// ---------------------------------------------------------------------------
__global__ __launch_bounds__(256) void k_make_M(const float* __restrict__ att,
                                                const float* __restrict__ basis,
                                                const float* __restrict__ fcw,
                                                ushort_t* __restrict__ Mt) {
    int tid = blockIdx.x * 256 + threadIdx.x;
    if (tid >= RR * FF * OUTD) return;
    int r = tid / (FF * OUTD);
    int rem = tid - r * FF * OUTD;
    int f = rem >> 6;
    int o = rem & 63;
    float a0 = att[r * 2 + 0], a1 = att[r * 2 + 1];
    const float* b0 = basis + f * EFFD;
    const float* b1 = basis + FF * EFFD + f * EFFD;
    float acc = 0.f;
#pragma unroll 4
    for (int e = 0; e < EFFD; ++e) {
        float w = a0 * b0[e] + a1 * b1[e];
        acc += w * fcw[e * OUTD + o];
    }
    Mt[(size_t)(r * OUTD + o) * FF + f] = f2bf(acc);
}

// ---------------------------------------------------------------------------
// Kernel B (MFMA): g[r][n][o] = bf16( cj[n] * sum_k feat[n][k] * M[k][r*64+o] )
// ---------------------------------------------------------------------------
__global__ __launch_bounds__(256) void k_gemm(const float* __restrict__ featA,
                                              const float* __restrict__ cjA,
                                              const float* __restrict__ featB,
                                              const float* __restrict__ cjB,
                                              const ushort_t* __restrict__ Mt,
                                              ushort_t* __restrict__ gA,
                                              ushort_t* __restrict__ gB) {
    const float* feat; const float* cj; ushort_t* g;
    if (blockIdx.z == 0) { feat = featA; cj = cjA; g = gA; }
    else                 { feat = featB; cj = cjB; g = gB; }

    __shared__ ushort_t featS[64][136];
    __shared__ ushort_t mtS[160][136];

    const int tid  = threadIdx.x;
    const int row0 = blockIdx.x * 64;
    const int ch0  = blockIdx.y * 160;

    for (int i = tid; i < 64 * 32; i += 256) {
        int r  = i >> 5;
        int c4 = (i & 31) << 2;
        float4 v = make_float4(0.f, 0.f, 0.f, 0.f);
        int row = row0 + r;
        if (row < NDRUG) v = *(const float4*)(feat + (size_t)row * FF + c4);
        ushort4 pk;
        pk.x = f2bf(v.x); pk.y = f2bf(v.y); pk.z = f2bf(v.z); pk.w = f2bf(v.w);
        *(ushort4*)&featS[r][c4] = pk;
    }
    for (int i = tid; i < 160 * 16; i += 256) {
        int c  = i >> 4;
        int q8 = (i & 15) << 3;
        *(short8*)&mtS[c][q8] = *(const short8*)(Mt + (size_t)(ch0 + c) * FF + q8);
    }
    __syncthreads();

    const int w = tid >> 6;
    const int l = tid & 63;
    const int lr = l & 15;
    const int lg = l >> 4;

    short8 afrag[4];
#pragma unroll
    for (int ks = 0; ks < 4; ++ks)
        afrag[ks] = *(const short8*)&featS[w * 16 + lr][ks * 32 + lg * 8];

    const int rbase = row0 + w * 16 + (lg << 2);
    float cjv[4];
#pragma unroll
    for (int rg = 0; rg < 4; ++rg)
        cjv[rg] = (rbase + rg < NDRUG) ? cj[rbase + rg] : 0.f;

#pragma unroll
    for (int n = 0; n < 10; ++n) {
        f32x4 c = {0.f, 0.f, 0.f, 0.f};
#pragma unroll
        for (int ks = 0; ks < 4; ++ks) {
            short8 b = *(const short8*)&mtS[n * 16 + lr][ks * 32 + lg * 8];
            c = __builtin_amdgcn_mfma_f32_16x16x32_bf16(afrag[ks], b, c, 0, 0, 0);
        }
        int col = ch0 + n * 16 + lr;
        int rr  = col >> 6;          // rating
        int oo  = col & 63;          // output col within rating
#pragma unroll
        for (int rg = 0; rg < 4; ++rg) {
            int row = rbase + rg;
            if (row < NDRUG)
                g[((size_t)rr * NDRUG + row) * OUTD + oo] = f2bf(c[rg] * cjv[rg]);
        }
    }
}

// ---------------------------------------------------------------------------
// Pass 1: coarse partition, dir-only split (deterministic staging, dense
// bulk-reserved writes). grid: (NCHUNKE*2, RR).
// Entry: ((dst&255)<<16 | src) into slotted bucket (dir, r, dst>>8).
// ---------------------------------------------------------------------------
__global__ __launch_bounds__(256) void k_part(const int* __restrict__ ed,
                                              const int* __restrict__ ei,
                                              int* __restrict__ tails,
                                              uint_t* __restrict__ coarse) {
    int dir = blockIdx.x & 1;
    int chunk = blockIdx.x >> 1;
    int r = blockIdx.y;
    const int* dstarr = (dir ? ed : ei) + (size_t)r * EE;
    const int* srcarr = (dir ? ei : ed) + (size_t)r * EE;
    int* tl = tails + (dir * RR + r) * NBKT;
    uint_t* cb = coarse + (size_t)(dir * RR + r) * NBKT * CAP;

    __shared__ uint_t stage[CHUNKE];   // 25 KB
    __shared__ int cnt[NBKT];
    __shared__ int cur[NBKT];
    __shared__ int gpos[NBKT];

    int t = threadIdx.x;
    if (t < NBKT) { cnt[t] = 0; cur[t] = 0; }
    __syncthreads();

    int e0 = chunk * CHUNKE;
    for (int i = t; i < CHUNKE; i += 256) {
        int d = __builtin_nontemporal_load(dstarr + e0 + i);
        int s = __builtin_nontemporal_load(srcarr + e0 + i);
        int b = d >> 8;
        stage[i] = ((uint_t)b << 24) | ((uint_t)(d & 255) << 16) | (uint_t)(ushort_t)s;
        atomicAdd(&cnt[b], 1);
    }
    __syncthreads();

    if (t < NBKT) gpos[t] = atomicAdd(&tl[t], cnt[t]);
    __syncthreads();

    for (int i = t; i < CHUNKE; i += 256) {
        uint_t e = stage[i];
        int b = e >> 24;
        int q = atomicAdd(&cur[b], 1);
        int idx = gpos[b] + q;
        if (idx < CAP)
            cb[(size_t)b * CAP + idx] = e & 0x00FFFFFFu;
    }
}

// ---------------------------------------------------------------------------
// Pass 2 (merged fine-sort + aggregation): one block per coarse bucket.
// LDS counting sort (hist -> scan -> scatter src into lsorted[4096]); then
// 4 waves x 64 bins each: per-edge src via ds_read_u16 (16 lanes share the
// address -> broadcast), 16-lane uint2 gathers (4 edges per instr group),
// quarter shfl_xor reduce, fused ci+bias float4 store.
// grid: (NBKT, RR, 2)
// ---------------------------------------------------------------------------
__global__ __launch_bounds__(256) void k_fuse(const ushort_t* __restrict__ gd,
                                              const ushort_t* __restrict__ gi,
                                              const int* __restrict__ tails,
                                              const uint_t* __restrict__ coarse,
                                              const float* __restrict__ ci_drug,
                                              const float* __restrict__ ci_dis,
                                              const float* __restrict__ fcb,
                                              float* __restrict__ out_drug,
                                              float* __restrict__ out_dis) {
    int b = blockIdx.x, r = blockIdx.y, dir = blockIdx.z;
    const ushort_t* g = dir ? gi : gd;
    const float* ci   = dir ? ci_drug : ci_dis;
    float* outp       = dir ? out_drug : out_dis;

    int gb = (dir * RR + r) * NBKT + b;
    const uint_t* cb = coarse + (size_t)gb * CAP;
    int count = tails[gb]; if (count > CAP) count = CAP;

    __shared__ ushort_t lsorted[CAP];   // 8 KB
    __shared__ int hist[256];
    __shared__ int incl[256];
    __shared__ int cur[256];

    int t = threadIdx.x;
    hist[t] = 0;
    __syncthreads();
    for (int i = t; i < count; i += 256)
        atomicAdd(&hist[cb[i] >> 16], 1);
    __syncthreads();

    int v = hist[t];
    incl[t] = v;
    __syncthreads();
    for (int off = 1; off < 256; off <<= 1) {
        int x = (t >= off) ? incl[t - off] : 0;
        __syncthreads();
        incl[t] += x;
        __syncthreads();
    }
    cur[t] = incl[t] - v;
    __syncthreads();

    for (int i = t; i < count; i += 256) {
        uint_t e = cb[i];
        int p = atomicAdd(&cur[e >> 16], 1);
        lsorted[p] = (ushort_t)e;
    }
    __syncthreads();

    // aggregation: wave w -> bins w*64 .. w*64+63
    const int w       = t >> 6;
    const int lane    = t & 63;
    const int quarter = lane >> 4;
    const int q       = lane & 15;
    const ushort_t* grow = g + (size_t)r * NDRUG * OUTD + q * 4;
    const float4 bb = *(const float4*)(fcb + q * 4);

    for (int ib = 0; ib < 64; ++ib) {
        int dstlow = w * 64 + ib;
        int dst = b * 256 + dstlow;
        if (dst >= NDIS) break;
        int start = dstlow ? incl[dstlow - 1] : 0;
        int end = incl[dstlow];

        float a0 = 0.f, a1 = 0.f, a2 = 0.f, a3 = 0.f;
        for (int j = start; j < end; j += 8) {
            uint2 u[2];
#pragma unroll
            for (int k = 0; k < 2; ++k) {
                int jj = j + 4 * k + quarter;
                int cl = jj < end ? jj : j;
                int sj = (int)lsorted[cl];
                u[k] = *(const uint2*)(grow + (size_t)sj * OUTD);
            }
#pragma unroll
            for (int k = 0; k < 2; ++k) {
                int jj = j + 4 * k + quarter;
                uint_t ux = jj < end ? u[k].x : 0u;
                uint_t uy = jj < end ? u[k].y : 0u;
                a0 += __uint_as_float(ux << 16);
                a1 += __uint_as_float(ux & 0xffff0000u);
                a2 += __uint_as_float(uy << 16);
                a3 += __uint_as_float(uy & 0xffff0000u);
            }
        }
        a0 += __shfl_xor(a0, 16); a1 += __shfl_xor(a1, 16);
        a2 += __shfl_xor(a2, 16); a3 += __shfl_xor(a3, 16);
        a0 += __shfl_xor(a0, 32); a1 += __shfl_xor(a1, 32);
        a2 += __shfl_xor(a2, 32); a3 += __shfl_xor(a3, 32);
        if (quarter == 0) {
            float civ = ci[dst];
            float4 o;
            o.x = a0 * civ + bb.x;
            o.y = a1 * civ + bb.y;
            o.z = a2 * civ + bb.z;
            o.w = a3 * civ + bb.w;
            *(float4*)(outp + (size_t)dst * NCOL + r * OUTD + q * 4) = o;
        }
    }
}

// ---------------------------------------------------------------------------
extern "C" void kernel_launch(void* const* d_in, const int* in_sizes, int n_in,
                              void* d_out, int out_size, void* d_ws, size_t ws_size,
                              hipStream_t stream) {
    const float* drug_feat = (const float*)d_in[0];
    const float* dis_feat  = (const float*)d_in[1];
    const float* cj_drug   = (const float*)d_in[2];
    const float* ci_drug   = (const float*)d_in[3];
    const float* cj_dis    = (const float*)d_in[4];
    const float* ci_dis    = (const float*)d_in[5];
    const float* att       = (const float*)d_in[6];
    const float* basis     = (const float*)d_in[7];
    const float* fcw       = (const float*)d_in[8];
    const float* fcb       = (const float*)d_in[9];
    const int*   edge_drug = (const int*)d_in[10];
    const int*   edge_dis  = (const int*)d_in[11];

    float* out      = (float*)d_out;
    float* out_drug = out;
    float* out_dis  = out + (size_t)NDRUG * NCOL;

    // Workspace layout (~98.3 MB):
    //   gd (bf16, [R][N][64])   32,000,000 @ 0
    //   gi (bf16, [R][N][64])   32,000,000 @ 32,000,000
    //   Mt (bf16)      163,840 @ 64,000,000
    //   tails (int)      7,840 @ 66,200,000
    //   coarse (u32) 32,112,640 @ 66,208,000
    char* ws = (char*)d_ws;
    ushort_t* gd      = (ushort_t*)ws;
    ushort_t* gi      = (ushort_t*)(ws + 32000000);
    ushort_t* Mtb     = (ushort_t*)(ws + 64000000);
    int*      tails   = (int*)(ws + 66200000);
    uint_t*   coarse  = (uint_t*)(ws + 66208000);

    // zero bucket tails
    hipMemsetAsync(tails, 0, NGB * sizeof(int), stream);

    // A: fused att*basis*fc_w -> Mt bf16 [320][128]
    k_make_M<<<dim3((RR * FF * OUTD + 255) / 256), 256, 0, stream>>>(att, basis, fcw, Mtb);

    // B: g = bf16((feat @ M) * cj), both sides (MFMA), rating-major layout
    dim3 ggrid((NDRUG + 63) / 64, 2, 2);
    k_gemm<<<ggrid, 256, 0, stream>>>(drug_feat, cj_drug, dis_feat, cj_dis, Mtb, gd, gi);

    // Coarse partition (dense writes, block-aggregated reservations)
    k_part<<<dim3(NCHUNKE * 2, RR), 256, 0, stream>>>(edge_drug, edge_dis, tails, coarse);

    // Merged fine-sort + gather aggregation + fused ci-scale + bias
    k_fuse<<<dim3(NBKT, RR, 2), 256, 0, stream>>>(gd, gi, tails, coarse,
                                                  ci_drug, ci_dis, fcb,
                                                  out_drug, out_dis);
}

// Round 15
// 225.620 us; speedup vs baseline: 1.5434x; 1.0489x over previous
//
#include <hip/hip_runtime.h>

// Problem constants
#define NDRUG 50000
#define NDIS  50000
#define RR    5
#define FF    128
#define EFFD  128
#define OUTD  64
#define EE    400000
#define NCOL  (RR * OUTD)        // 320 columns in fused OUTPUT layout [n][r*64+o]
#define NEDGE (RR * EE)          // 2,000,000 edges per direction

// Two-level bucket sort
#define NBKT    196              // coarse buckets per (dir,r): dst>>8 (50000/256)
#define CAP     4096             // slot capacity per bucket (avg fill 2048, ~45 sigma headroom)
#define NGB     (2 * RR * NBKT)  // 1960 global buckets

#define NCHUNKE 128              // edge chunks per r (both dirs handled per block)
#define CHUNKE  (EE / NCHUNKE)   // 3125 edges per chunk (exact)

typedef unsigned short ushort_t;
typedef unsigned int uint_t;
typedef short short8 __attribute__((ext_vector_type(8)));
typedef float f32x4 __attribute__((ext_vector_type(4)));
typedef float f32x2 __attribute__((ext_vector_type(2)));

// f32 -> bf16 round-to-nearest-even
static __device__ __forceinline__ ushort_t f2bf(float f) {
    uint_t u = __float_as_uint(f);
    uint_t r = (u + 0x7FFFu + ((u >> 16) & 1u)) >> 16;
    return (ushort_t)r;
}

// ---------------------------------------------------------------------------
// Kernel A: Mt[col][f] = bf16( sum_e (att[r,0]*basis[0,f,e]+att[r,1]*basis[1,f,e]) * fc_w[e,o] )
// ---------------------------------------------------------------------------
__global__ __launch_bounds__(256) void k_make_M(const float* __restrict__ att,
                                                const float* __restrict__ basis,
                                                const float* __restrict__ fcw,
                                                ushort_t* __restrict__ Mt) {
    int tid = blockIdx.x * 256 + threadIdx.x;
    if (tid >= RR * FF * OUTD) return;
    int r = tid / (FF * OUTD);
    int rem = tid - r * FF * OUTD;
    int f = rem >> 6;
    int o = rem & 63;
    float a0 = att[r * 2 + 0], a1 = att[r * 2 + 1];
    const float* b0 = basis + f * EFFD;
    const float* b1 = basis + FF * EFFD + f * EFFD;
    float acc = 0.f;
#pragma unroll 4
    for (int e = 0; e < EFFD; ++e) {
        float w = a0 * b0[e] + a1 * b1[e];
        acc += w * fcw[e * OUTD + o];
    }
    Mt[(size_t)(r * OUTD + o) * FF + f] = f2bf(acc);
}

// ---------------------------------------------------------------------------
// Kernel B (MFMA): g[r][n][o] = bf16( cj[n] * sum_k feat[n][k] * M[k][r*64+o] )
// ---------------------------------------------------------------------------
__global__ __launch_bounds__(256) void k_gemm(const float* __restrict__ featA,
                                              const float* __restrict__ cjA,
                                              const float* __restrict__ featB,
                                              const float* __restrict__ cjB,
                                              const ushort_t* __restrict__ Mt,
                                              ushort_t* __restrict__ gA,
                                              ushort_t* __restrict__ gB) {
    const float* feat; const float* cj; ushort_t* g;
    if (blockIdx.z == 0) { feat = featA; cj = cjA; g = gA; }
    else                 { feat = featB; cj = cjB; g = gB; }

    __shared__ ushort_t featS[64][136];
    __shared__ ushort_t mtS[160][136];

    const int tid  = threadIdx.x;
    const int row0 = blockIdx.x * 64;
    const int ch0  = blockIdx.y * 160;

    for (int i = tid; i < 64 * 32; i += 256) {
        int r  = i >> 5;
        int c4 = (i & 31) << 2;
        float4 v = make_float4(0.f, 0.f, 0.f, 0.f);
        int row = row0 + r;
        if (row < NDRUG) v = *(const float4*)(feat + (size_t)row * FF + c4);
        ushort4 pk;
        pk.x = f2bf(v.x); pk.y = f2bf(v.y); pk.z = f2bf(v.z); pk.w = f2bf(v.w);
        *(ushort4*)&featS[r][c4] = pk;
    }
    for (int i = tid; i < 160 * 16; i += 256) {
        int c  = i >> 4;
        int q8 = (i & 15) << 3;
        *(short8*)&mtS[c][q8] = *(const short8*)(Mt + (size_t)(ch0 + c) * FF + q8);
    }
    __syncthreads();

    const int w = tid >> 6;
    const int l = tid & 63;
    const int lr = l & 15;
    const int lg = l >> 4;

    short8 afrag[4];
#pragma unroll
    for (int ks = 0; ks < 4; ++ks)
        afrag[ks] = *(const short8*)&featS[w * 16 + lr][ks * 32 + lg * 8];

    const int rbase = row0 + w * 16 + (lg << 2);
    float cjv[4];
#pragma unroll
    for (int rg = 0; rg < 4; ++rg)
        cjv[rg] = (rbase + rg < NDRUG) ? cj[rbase + rg] : 0.f;

#pragma unroll
    for (int n = 0; n < 10; ++n) {
        f32x4 c = {0.f, 0.f, 0.f, 0.f};
#pragma unroll
        for (int ks = 0; ks < 4; ++ks) {
            short8 b = *(const short8*)&mtS[n * 16 + lr][ks * 32 + lg * 8];
            c = __builtin_amdgcn_mfma_f32_16x16x32_bf16(afrag[ks], b, c, 0, 0, 0);
        }
        int col = ch0 + n * 16 + lr;
        int rr  = col >> 6;          // rating
        int oo  = col & 63;          // output col within rating
#pragma unroll
        for (int rg = 0; rg < 4; ++rg) {
            int row = rbase + rg;
            if (row < NDRUG)
                g[((size_t)rr * NDRUG + row) * OUTD + oo] = f2bf(c[rg] * cjv[rg]);
        }
    }
}

// ---------------------------------------------------------------------------
// Pass 1: coarse partition, BOTH directions per block (edge arrays read once).
// Entry: ((dst&255)<<16 | src) into slotted bucket (dir, r, dst>>8).
// grid: (NCHUNKE, RR). ~30 KB LDS -> good occupancy.
// ---------------------------------------------------------------------------
__global__ __launch_bounds__(256) void k_part(const int* __restrict__ ed,
                                              const int* __restrict__ ei,
                                              int* __restrict__ tails,
                                              uint_t* __restrict__ coarse) {
    int chunk = blockIdx.x;
    int r = blockIdx.y;
    const int* A = ed + (size_t)r * EE;   // drug endpoints
    const int* B = ei + (size_t)r * EE;   // disease endpoints
    // dir0: dst=B, src=A ; dir1: dst=A, src=B
    int* tl0 = tails + (0 * RR + r) * NBKT;
    int* tl1 = tails + (1 * RR + r) * NBKT;
    uint_t* cb0 = coarse + (size_t)(0 * RR + r) * NBKT * CAP;
    uint_t* cb1 = coarse + (size_t)(1 * RR + r) * NBKT * CAP;

    __shared__ uint_t stage0[CHUNKE];   // 12.5 KB
    __shared__ uint_t stage1[CHUNKE];   // 12.5 KB
    __shared__ int cnt[2 * NBKT];
    __shared__ int cur[2 * NBKT];
    __shared__ int gpos[2 * NBKT];

    int t = threadIdx.x;
    for (int u = t; u < 2 * NBKT; u += 256) { cnt[u] = 0; cur[u] = 0; }
    __syncthreads();

    int e0 = chunk * CHUNKE;
    for (int i = t; i < CHUNKE; i += 256) {
        int a = __builtin_nontemporal_load(A + e0 + i);
        int b = __builtin_nontemporal_load(B + e0 + i);
        uint_t en0 = ((uint_t)(b >> 8) << 24) | ((uint_t)(b & 255) << 16) | (uint_t)(ushort_t)a;
        uint_t en1 = ((uint_t)(a >> 8) << 24) | ((uint_t)(a & 255) << 16) | (uint_t)(ushort_t)b;
        stage0[i] = en0;
        stage1[i] = en1;
        atomicAdd(&cnt[b >> 8], 1);
        atomicAdd(&cnt[NBKT + (a >> 8)], 1);
    }
    __syncthreads();

    for (int u = t; u < 2 * NBKT; u += 256) {
        int* tl = (u < NBKT) ? tl0 : tl1;
        int bb = (u < NBKT) ? u : u - NBKT;
        gpos[u] = atomicAdd(&tl[bb], cnt[u]);
    }
    __syncthreads();

    for (int i = t; i < CHUNKE; i += 256) {
        uint_t e = stage0[i];
        int b = e >> 24;
        int q = atomicAdd(&cur[b], 1);
        int idx = gpos[b] + q;
        if (idx < CAP)
            cb0[(size_t)b * CAP + idx] = e & 0x00FFFFFFu;
    }
    for (int i = t; i < CHUNKE; i += 256) {
        uint_t e = stage1[i];
        int b = e >> 24;
        int q = atomicAdd(&cur[NBKT + b], 1);
        int idx = gpos[NBKT + b] + q;
        if (idx < CAP)
            cb1[(size_t)b * CAP + idx] = e & 0x00FFFFFFu;
    }
}

// ---------------------------------------------------------------------------
// Pass 2 (merged fine-sort + aggregation): one block per coarse bucket.
// XCD-contiguous bucket remap: flat grid 1960, block bid -> XCD bid&7 (round
// robin); gb = (bid&7)*245 + (bid>>3) gives each XCD a CONTIGUOUS 245-bucket
// range spanning <=2 (dir,r) gather regions (<=12.8 MB) instead of all 10
// (64 MB) -> per-XCD L2 stops phase-thrashing.
// LDS counting sort, then 4 waves x 64 bins, 16-lane uint2 gathers, packed
// f32x2 accumulate (v_pk_add_f32), quarter shfl_xor reduce, fused ci+bias.
// ---------------------------------------------------------------------------
__global__ __launch_bounds__(256) void k_fuse(const ushort_t* __restrict__ gd,
                                              const ushort_t* __restrict__ gi,
                                              const int* __restrict__ tails,
                                              const uint_t* __restrict__ coarse,
                                              const float* __restrict__ ci_drug,
                                              const float* __restrict__ ci_dis,
                                              const float* __restrict__ fcb,
                                              float* __restrict__ out_drug,
                                              float* __restrict__ out_dis) {
    int bid = blockIdx.x;
    int gb = (bid & 7) * (NGB / 8) + (bid >> 3);   // XCD-contiguous range
    int dir = gb / (RR * NBKT);
    int rem = gb - dir * (RR * NBKT);
    int r = rem / NBKT;
    int b = rem - r * NBKT;

    const ushort_t* g = dir ? gi : gd;
    const float* ci   = dir ? ci_drug : ci_dis;
    float* outp       = dir ? out_drug : out_dis;

    const uint_t* cb = coarse + (size_t)gb * CAP;
    int count = tails[gb]; if (count > CAP) count = CAP;

    __shared__ ushort_t lsorted[CAP];   // 8 KB
    __shared__ int hist[256];
    __shared__ int incl[256];
    __shared__ int cur[256];

    int t = threadIdx.x;
    hist[t] = 0;
    __syncthreads();
    for (int i = t; i < count; i += 256)
        atomicAdd(&hist[cb[i] >> 16], 1);
    __syncthreads();

    int v = hist[t];
    incl[t] = v;
    __syncthreads();
    for (int off = 1; off < 256; off <<= 1) {
        int x = (t >= off) ? incl[t - off] : 0;
        __syncthreads();
        incl[t] += x;
        __syncthreads();
    }
    cur[t] = incl[t] - v;
    __syncthreads();

    for (int i = t; i < count; i += 256) {
        uint_t e = cb[i];
        int p = atomicAdd(&cur[e >> 16], 1);
        lsorted[p] = (ushort_t)e;
    }
    __syncthreads();

    // aggregation: wave w -> bins w*64 .. w*64+63
    const int w       = t >> 6;
    const int lane    = t & 63;
    const int quarter = lane >> 4;
    const int q       = lane & 15;
    const ushort_t* grow = g + (size_t)r * NDRUG * OUTD + q * 4;
    const float4 bb = *(const float4*)(fcb + q * 4);

    for (int ib = 0; ib < 64; ++ib) {
        int dstlow = w * 64 + ib;
        int dst = b * 256 + dstlow;
        if (dst >= NDIS) break;
        int start = dstlow ? incl[dstlow - 1] : 0;
        int end = incl[dstlow];

        f32x2 a01 = {0.f, 0.f}, a23 = {0.f, 0.f};
        for (int j = start; j < end; j += 8) {
            uint2 u[2];
#pragma unroll
            for (int k = 0; k < 2; ++k) {
                int jj = j + 4 * k + quarter;
                int cl = jj < end ? jj : j;
                int sj = (int)lsorted[cl];
                u[k] = *(const uint2*)(grow + (size_t)sj * OUTD);
            }
#pragma unroll
            for (int k = 0; k < 2; ++k) {
                int jj = j + 4 * k + quarter;
                uint_t ux = jj < end ? u[k].x : 0u;
                uint_t uy = jj < end ? u[k].y : 0u;
                f32x2 p0 = { __uint_as_float(ux << 16), __uint_as_float(ux & 0xffff0000u) };
                f32x2 p1 = { __uint_as_float(uy << 16), __uint_as_float(uy & 0xffff0000u) };
                a01 += p0;
                a23 += p1;
            }
        }
        float a0 = a01.x, a1 = a01.y, a2 = a23.x, a3 = a23.y;
        a0 += __shfl_xor(a0, 16); a1 += __shfl_xor(a1, 16);
        a2 += __shfl_xor(a2, 16); a3 += __shfl_xor(a3, 16);
        a0 += __shfl_xor(a0, 32); a1 += __shfl_xor(a1, 32);
        a2 += __shfl_xor(a2, 32); a3 += __shfl_xor(a3, 32);
        if (quarter == 0) {
            float civ = ci[dst];
            float4 o;
            o.x = a0 * civ + bb.x;
            o.y = a1 * civ + bb.y;
            o.z = a2 * civ + bb.z;
            o.w = a3 * civ + bb.w;
            *(float4*)(outp + (size_t)dst * NCOL + r * OUTD + q * 4) = o;
        }
    }
}

// ---------------------------------------------------------------------------
extern "C" void kernel_launch(void* const* d_in, const int* in_sizes, int n_in,
                              void* d_out, int out_size, void* d_ws, size_t ws_size,
                              hipStream_t stream) {
    const float* drug_feat = (const float*)d_in[0];
    const float* dis_feat  = (const float*)d_in[1];
    const float* cj_drug   = (const float*)d_in[2];
    const float* ci_drug   = (const float*)d_in[3];
    const float* cj_dis    = (const float*)d_in[4];
    const float* ci_dis    = (const float*)d_in[5];
    const float* att       = (const float*)d_in[6];
    const float* basis     = (const float*)d_in[7];
    const float* fcw       = (const float*)d_in[8];
    const float* fcb       = (const float*)d_in[9];
    const int*   edge_drug = (const int*)d_in[10];
    const int*   edge_dis  = (const int*)d_in[11];

    float* out      = (float*)d_out;
    float* out_drug = out;
    float* out_dis  = out + (size_t)NDRUG * NCOL;

    // Workspace layout (~98.3 MB):
    //   gd (bf16, [R][N][64])   32,000,000 @ 0
    //   gi (bf16, [R][N][64])   32,000,000 @ 32,000,000
    //   Mt (bf16)      163,840 @ 64,000,000
    //   tails (int)      7,840 @ 66,200,000
    //   coarse (u32) 32,112,640 @ 66,208,000
    char* ws = (char*)d_ws;
    ushort_t* gd      = (ushort_t*)ws;
    ushort_t* gi      = (ushort_t*)(ws + 32000000);
    ushort_t* Mtb     = (ushort_t*)(ws + 64000000);
    int*      tails   = (int*)(ws + 66200000);
    uint_t*   coarse  = (uint_t*)(ws + 66208000);

    // zero bucket tails
    hipMemsetAsync(tails, 0, NGB * sizeof(int), stream);

    // A: fused att*basis*fc_w -> Mt bf16 [320][128]
    k_make_M<<<dim3((RR * FF * OUTD + 255) / 256), 256, 0, stream>>>(att, basis, fcw, Mtb);

    // B: g = bf16((feat @ M) * cj), both sides (MFMA), rating-major layout
    dim3 ggrid((NDRUG + 63) / 64, 2, 2);
    k_gemm<<<ggrid, 256, 0, stream>>>(drug_feat, cj_drug, dis_feat, cj_dis, Mtb, gd, gi);

    // Coarse partition (both dirs per block; dense bulk-reserved writes)
    k_part<<<dim3(NCHUNKE, RR), 256, 0, stream>>>(edge_drug, edge_dis, tails, coarse);

    // Merged fine-sort + gather aggregation + fused ci-scale + bias
    k_fuse<<<dim3(NGB), 256, 0, stream>>>(gd, gi, tails, coarse,
                                          ci_drug, ci_dis, fcb,
                                          out_drug, out_dis);
}

// Round 17
// 223.494 us; speedup vs baseline: 1.5581x; 1.0095x over previous
//
#include <hip/hip_runtime.h>

// Problem constants
#define NDRUG 50000
#define NDIS  50000
#define RR    5
#define FF    128
#define EFFD  128
#define OUTD  64
#define EE    400000
#define NCOL  (RR * OUTD)        // 320 columns in fused OUTPUT layout [n][r*64+o]
#define NEDGE (RR * EE)          // 2,000,000 edges per direction

// Two-level bucket sort
#define NBKT    196              // coarse buckets per (dir,r): dst>>8 (50000/256)
#define CAP     4096             // slot capacity per bucket (avg fill 2048, ~45 sigma headroom)
#define NGB     (2 * RR * NBKT)  // 1960 global buckets

#define NCHUNKE 128              // edge chunks per r (both dirs handled per block)
#define CHUNKE  (EE / NCHUNKE)   // 3125 edges per chunk (exact)

// merged part+gemm dispatch geometry
#define PART_BLOCKS (NCHUNKE * RR)            // 640
#define GEMM_RB     ((NDRUG + 63) / 64)       // 782 row-blocks
#define GEMM_BLOCKS (GEMM_RB * 4)             // x2 col-half x2 side = 3128
#define PG_BLOCKS   (PART_BLOCKS + GEMM_BLOCKS)

typedef unsigned short ushort_t;
typedef unsigned int uint_t;
typedef short short8 __attribute__((ext_vector_type(8)));
typedef float f32x4 __attribute__((ext_vector_type(4)));
typedef float f32x2 __attribute__((ext_vector_type(2)));

// f32 -> bf16 round-to-nearest-even
static __device__ __forceinline__ ushort_t f2bf(float f) {
    uint_t u = __float_as_uint(f);
    uint_t r = (u + 0x7FFFu + ((u >> 16) & 1u)) >> 16;
    return (ushort_t)r;
}

// ---------------------------------------------------------------------------
// Kernel A: Mt[col][f] = bf16( sum_e (att[r,0]*basis[0,f,e]+att[r,1]*basis[1,f,e]) * fc_w[e,o] )
// ---------------------------------------------------------------------------
__global__ __launch_bounds__(256) void k_make_M(const float* __restrict__ att,
                                                const float* __restrict__ basis,
                                                const float* __restrict__ fcw,
                                                ushort_t* __restrict__ Mt) {
    int tid = blockIdx.x * 256 + threadIdx.x;
    if (tid >= RR * FF * OUTD) return;
    int r = tid / (FF * OUTD);
    int rem = tid - r * FF * OUTD;
    int f = rem >> 6;
    int o = rem & 63;
    float a0 = att[r * 2 + 0], a1 = att[r * 2 + 1];
    const float* b0 = basis + f * EFFD;
    const float* b1 = basis + FF * EFFD + f * EFFD;
    float acc = 0.f;
#pragma unroll 4
    for (int e = 0; e < EFFD; ++e) {
        float w = a0 * b0[e] + a1 * b1[e];
        acc += w * fcw[e * OUTD + o];
    }
    Mt[(size_t)(r * OUTD + o) * FF + f] = f2bf(acc);
}

// ---------------------------------------------------------------------------
// Merged Pass 1: part-blocks (bid < PART_BLOCKS) bucket the edges;
// gemm-blocks (bid >= PART_BLOCKS) compute g = bf16((feat @ M) * cj).
// The two roles have no data dependency; interleaved scheduling hides the
// LDS-atomic-bound part work under the MFMA/memory-bound gemm work.
// ---------------------------------------------------------------------------
union SharedPG {
    struct {
        ushort_t featS[64][136];
        ushort_t mtS[160][136];
    } g;                                   // 60.9 KB
    struct {
        uint_t stage0[CHUNKE];
        uint_t stage1[CHUNKE];
        int cnt[2 * NBKT];
        int cur[2 * NBKT];
        int gpos[2 * NBKT];
    } p;                                   // 29.7 KB
};

__global__ __launch_bounds__(256) void k_pg(const int* __restrict__ ed,
                                            const int* __restrict__ ei,
                                            int* __restrict__ tails,
                                            uint_t* __restrict__ coarse,
                                            const float* __restrict__ featA,
                                            const float* __restrict__ cjA,
                                            const float* __restrict__ featB,
                                            const float* __restrict__ cjB,
                                            const ushort_t* __restrict__ Mt,
                                            ushort_t* __restrict__ gA,
                                            ushort_t* __restrict__ gB) {
    __shared__ SharedPG sh;
    const int bid = blockIdx.x;
    const int t = threadIdx.x;

    if (bid < PART_BLOCKS) {
        // ---------------- coarse partition (both dirs per block) -----------
        int chunk = bid & (NCHUNKE - 1);
        int r = bid >> 7;
        const int* A = ed + (size_t)r * EE;   // drug endpoints
        const int* B = ei + (size_t)r * EE;   // disease endpoints
        int* tl0 = tails + (0 * RR + r) * NBKT;
        int* tl1 = tails + (1 * RR + r) * NBKT;
        uint_t* cb0 = coarse + (size_t)(0 * RR + r) * NBKT * CAP;
        uint_t* cb1 = coarse + (size_t)(1 * RR + r) * NBKT * CAP;

        for (int u = t; u < 2 * NBKT; u += 256) { sh.p.cnt[u] = 0; sh.p.cur[u] = 0; }
        __syncthreads();

        int e0 = chunk * CHUNKE;
        for (int i = t; i < CHUNKE; i += 256) {
            int a = __builtin_nontemporal_load(A + e0 + i);
            int b = __builtin_nontemporal_load(B + e0 + i);
            sh.p.stage0[i] = ((uint_t)(b >> 8) << 24) | ((uint_t)(b & 255) << 16) | (uint_t)(ushort_t)a;
            sh.p.stage1[i] = ((uint_t)(a >> 8) << 24) | ((uint_t)(a & 255) << 16) | (uint_t)(ushort_t)b;
            atomicAdd(&sh.p.cnt[b >> 8], 1);
            atomicAdd(&sh.p.cnt[NBKT + (a >> 8)], 1);
        }
        __syncthreads();

        for (int u = t; u < 2 * NBKT; u += 256) {
            int* tl = (u < NBKT) ? tl0 : tl1;
            int bb = (u < NBKT) ? u : u - NBKT;
            sh.p.gpos[u] = atomicAdd(&tl[bb], sh.p.cnt[u]);
        }
        __syncthreads();

        for (int i = t; i < CHUNKE; i += 256) {
            uint_t e = sh.p.stage0[i];
            int b = e >> 24;
            int q = atomicAdd(&sh.p.cur[b], 1);
            int idx = sh.p.gpos[b] + q;
            if (idx < CAP)
                cb0[(size_t)b * CAP + idx] = e & 0x00FFFFFFu;
        }
        for (int i = t; i < CHUNKE; i += 256) {
            uint_t e = sh.p.stage1[i];
            int b = e >> 24;
            int q = atomicAdd(&sh.p.cur[NBKT + b], 1);
            int idx = sh.p.gpos[NBKT + b] + q;
            if (idx < CAP)
                cb1[(size_t)b * CAP + idx] = e & 0x00FFFFFFu;
        }
        return;
    }

    // ---------------- MFMA transform g[r][n][o] -----------------------------
    int gid = bid - PART_BLOCKS;
    int bx = gid % GEMM_RB;
    int qq = gid / GEMM_RB;          // 0..3
    int by = qq & 1;                 // col-half
    int bz = qq >> 1;                // side

    const float* feat; const float* cj; ushort_t* g;
    if (bz == 0) { feat = featA; cj = cjA; g = gA; }
    else         { feat = featB; cj = cjB; g = gB; }

    const int row0 = bx * 64;
    const int ch0  = by * 160;

    for (int i = t; i < 64 * 32; i += 256) {
        int r  = i >> 5;
        int c4 = (i & 31) << 2;
        float4 v = make_float4(0.f, 0.f, 0.f, 0.f);
        int row = row0 + r;
        if (row < NDRUG) v = *(const float4*)(feat + (size_t)row * FF + c4);
        ushort4 pk;
        pk.x = f2bf(v.x); pk.y = f2bf(v.y); pk.z = f2bf(v.z); pk.w = f2bf(v.w);
        *(ushort4*)&sh.g.featS[r][c4] = pk;
    }
    for (int i = t; i < 160 * 16; i += 256) {
        int c  = i >> 4;
        int q8 = (i & 15) << 3;
        *(short8*)&sh.g.mtS[c][q8] = *(const short8*)(Mt + (size_t)(ch0 + c) * FF + q8);
    }
    __syncthreads();

    const int w = t >> 6;
    const int l = t & 63;
    const int lr = l & 15;
    const int lg = l >> 4;

    short8 afrag[4];
#pragma unroll
    for (int ks = 0; ks < 4; ++ks)
        afrag[ks] = *(const short8*)&sh.g.featS[w * 16 + lr][ks * 32 + lg * 8];

    const int rbase = row0 + w * 16 + (lg << 2);
    float cjv[4];
#pragma unroll
    for (int rg = 0; rg < 4; ++rg)
        cjv[rg] = (rbase + rg < NDRUG) ? cj[rbase + rg] : 0.f;

#pragma unroll
    for (int n = 0; n < 10; ++n) {
        f32x4 c = {0.f, 0.f, 0.f, 0.f};
#pragma unroll
        for (int ks = 0; ks < 4; ++ks) {
            short8 b = *(const short8*)&sh.g.mtS[n * 16 + lr][ks * 32 + lg * 8];
            c = __builtin_amdgcn_mfma_f32_16x16x32_bf16(afrag[ks], b, c, 0, 0, 0);
        }
        int col = ch0 + n * 16 + lr;
        int rr  = col >> 6;
        int oo  = col & 63;
#pragma unroll
        for (int rg = 0; rg < 4; ++rg) {
            int row = rbase + rg;
            if (row < NDRUG)
                g[((size_t)rr * NDRUG + row) * OUTD + oo] = f2bf(c[rg] * cjv[rg]);
        }
    }
}

// ---------------------------------------------------------------------------
// Pass 2 (merged fine-sort + aggregation): one block per coarse bucket.
// XCD-contiguous bucket remap. Bucket entries are register-staged (16/thread,
// one NT global read total); LDS counting sort; then 4 waves x 64 bins with
// 16-lane uint2 gathers, packed f32x2 accumulate, quarter shfl_xor reduce,
// fused ci+bias NONTEMPORAL f32x4 store (out is never re-read).
// ---------------------------------------------------------------------------
__global__ __launch_bounds__(256) void k_fuse(const ushort_t* __restrict__ gd,
                                              const ushort_t* __restrict__ gi,
                                              const int* __restrict__ tails,
                                              const uint_t* __restrict__ coarse,
                                              const float* __restrict__ ci_drug,
                                              const float* __restrict__ ci_dis,
                                              const float* __restrict__ fcb,
                                              float* __restrict__ out_drug,
                                              float* __restrict__ out_dis) {
    int bid = blockIdx.x;
    int gb = (bid & 7) * (NGB / 8) + (bid >> 3);   // XCD-contiguous range
    int dir = gb / (RR * NBKT);
    int rem = gb - dir * (RR * NBKT);
    int r = rem / NBKT;
    int b = rem - r * NBKT;

    const ushort_t* g = dir ? gi : gd;
    const float* ci   = dir ? ci_drug : ci_dis;
    float* outp       = dir ? out_drug : out_dis;

    const uint_t* cb = coarse + (size_t)gb * CAP;
    int count = tails[gb]; if (count > CAP) count = CAP;

    __shared__ ushort_t lsorted[CAP];   // 8 KB
    __shared__ int hist[256];
    __shared__ int incl[256];
    __shared__ int cur[256];

    int t = threadIdx.x;

    // register-stage the bucket: one NT read of coarse
    uint_t ereg[16];
#pragma unroll
    for (int k = 0; k < 16; ++k) {
        int i = k * 256 + t;
        ereg[k] = (i < count) ? __builtin_nontemporal_load(cb + i) : 0xFFFFFFFFu;
    }

    hist[t] = 0;
    __syncthreads();
#pragma unroll
    for (int k = 0; k < 16; ++k)
        if (ereg[k] != 0xFFFFFFFFu)
            atomicAdd(&hist[(ereg[k] >> 16) & 255], 1);
    __syncthreads();

    int v = hist[t];
    incl[t] = v;
    __syncthreads();
    for (int off = 1; off < 256; off <<= 1) {
        int x = (t >= off) ? incl[t - off] : 0;
        __syncthreads();
        incl[t] += x;
        __syncthreads();
    }
    cur[t] = incl[t] - v;
    __syncthreads();

#pragma unroll
    for (int k = 0; k < 16; ++k) {
        uint_t e = ereg[k];
        if (e != 0xFFFFFFFFu) {
            int p = atomicAdd(&cur[(e >> 16) & 255], 1);
            lsorted[p] = (ushort_t)e;
        }
    }
    __syncthreads();

    // aggregation: wave w -> bins w*64 .. w*64+63
    const int w       = t >> 6;
    const int lane    = t & 63;
    const int quarter = lane >> 4;
    const int q       = lane & 15;
    const ushort_t* grow = g + (size_t)r * NDRUG * OUTD + q * 4;
    const float4 bb = *(const float4*)(fcb + q * 4);

    for (int ib = 0; ib < 64; ++ib) {
        int dstlow = w * 64 + ib;
        int dst = b * 256 + dstlow;
        if (dst >= NDIS) break;
        int start = dstlow ? incl[dstlow - 1] : 0;
        int end = incl[dstlow];

        f32x2 a01 = {0.f, 0.f}, a23 = {0.f, 0.f};
        for (int j = start; j < end; j += 8) {
            uint2 u[2];
#pragma unroll
            for (int k = 0; k < 2; ++k) {
                int jj = j + 4 * k + quarter;
                int cl = jj < end ? jj : j;
                int sj = (int)lsorted[cl];
                u[k] = *(const uint2*)(grow + (size_t)sj * OUTD);
            }
#pragma unroll
            for (int k = 0; k < 2; ++k) {
                int jj = j + 4 * k + quarter;
                uint_t ux = jj < end ? u[k].x : 0u;
                uint_t uy = jj < end ? u[k].y : 0u;
                f32x2 p0 = { __uint_as_float(ux << 16), __uint_as_float(ux & 0xffff0000u) };
                f32x2 p1 = { __uint_as_float(uy << 16), __uint_as_float(uy & 0xffff0000u) };
                a01 += p0;
                a23 += p1;
            }
        }
        float a0 = a01.x, a1 = a01.y, a2 = a23.x, a3 = a23.y;
        a0 += __shfl_xor(a0, 16); a1 += __shfl_xor(a1, 16);
        a2 += __shfl_xor(a2, 16); a3 += __shfl_xor(a3, 16);
        a0 += __shfl_xor(a0, 32); a1 += __shfl_xor(a1, 32);
        a2 += __shfl_xor(a2, 32); a3 += __shfl_xor(a3, 32);
        if (quarter == 0) {
            float civ = ci[dst];
            f32x4 o;
            o.x = a0 * civ + bb.x;
            o.y = a1 * civ + bb.y;
            o.z = a2 * civ + bb.z;
            o.w = a3 * civ + bb.w;
            __builtin_nontemporal_store(o,
                (f32x4*)(outp + (size_t)dst * NCOL + r * OUTD + q * 4));
        }
    }
}

// ---------------------------------------------------------------------------
extern "C" void kernel_launch(void* const* d_in, const int* in_sizes, int n_in,
                              void* d_out, int out_size, void* d_ws, size_t ws_size,
                              hipStream_t stream) {
    const float* drug_feat = (const float*)d_in[0];
    const float* dis_feat  = (const float*)d_in[1];
    const float* cj_drug   = (const float*)d_in[2];
    const float* ci_drug   = (const float*)d_in[3];
    const float* cj_dis    = (const float*)d_in[4];
    const float* ci_dis    = (const float*)d_in[5];
    const float* att       = (const float*)d_in[6];
    const float* basis     = (const float*)d_in[7];
    const float* fcw       = (const float*)d_in[8];
    const float* fcb       = (const float*)d_in[9];
    const int*   edge_drug = (const int*)d_in[10];
    const int*   edge_dis  = (const int*)d_in[11];

    float* out      = (float*)d_out;
    float* out_drug = out;
    float* out_dis  = out + (size_t)NDRUG * NCOL;

    // Workspace layout (~98.3 MB):
    //   gd (bf16, [R][N][64])   32,000,000 @ 0
    //   gi (bf16, [R][N][64])   32,000,000 @ 32,000,000
    //   Mt (bf16)      163,840 @ 64,000,000
    //   tails (int)      7,840 @ 66,200,000
    //   coarse (u32) 32,112,640 @ 66,208,000
    char* ws = (char*)d_ws;
    ushort_t* gd      = (ushort_t*)ws;
    ushort_t* gi      = (ushort_t*)(ws + 32000000);
    ushort_t* Mtb     = (ushort_t*)(ws + 64000000);
    int*      tails   = (int*)(ws + 66200000);
    uint_t*   coarse  = (uint_t*)(ws + 66208000);

    // zero bucket tails
    hipMemsetAsync(tails, 0, NGB * sizeof(int), stream);

    // A: fused att*basis*fc_w -> Mt bf16 [320][128]
    k_make_M<<<dim3((RR * FF * OUTD + 255) / 256), 256, 0, stream>>>(att, basis, fcw, Mtb);

    // Merged: coarse partition (blocks 0..639) + MFMA transform (rest)
    k_pg<<<dim3(PG_BLOCKS), 256, 0, stream>>>(edge_drug, edge_dis, tails, coarse,
                                              drug_feat, cj_drug, dis_feat, cj_dis,
                                              Mtb, gd, gi);

    // Merged fine-sort + gather aggregation + fused ci-scale + bias
    k_fuse<<<dim3(NGB), 256, 0, stream>>>(gd, gi, tails, coarse,
                                          ci_drug, ci_dis, fcb,
                                          out_drug, out_dis);
}

// Round 18
// 203.561 us; speedup vs baseline: 1.7107x; 1.0979x over previous
//
#include <hip/hip_runtime.h>

// Problem constants
#define NDRUG 50000
#define NDIS  50000
#define RR    5
#define FF    128
#define EFFD  128
#define OUTD  64
#define EE    400000
#define NCOL  (RR * OUTD)        // 320 columns in fused OUTPUT layout [n][r*64+o]
#define NEDGE (RR * EE)          // 2,000,000 edges per direction

// Two-level bucket sort
#define NBKT    196              // coarse buckets per (dir,r): dst>>8 (50000/256)
#define CAP     4096             // slot capacity per bucket (avg fill 2048, ~45 sigma headroom)
#define NGB     (2 * RR * NBKT)  // 1960 global buckets

#define NCHUNKE 128              // edge chunks per r (both dirs handled per block)
#define CHUNKE  (EE / NCHUNKE)   // 3125 edges per chunk (exact)

// merged part+gemm dispatch geometry
#define PART_BLOCKS (NCHUNKE * RR)            // 640
#define GEMM_RB     ((NDRUG + 63) / 64)       // 782 row-blocks
#define GEMM_BLOCKS (GEMM_RB * 4)             // x2 col-half x2 side = 3128
#define PG_BLOCKS   (PART_BLOCKS + GEMM_BLOCKS)

typedef unsigned short ushort_t;
typedef unsigned int uint_t;
typedef short short8 __attribute__((ext_vector_type(8)));
typedef float f32x4 __attribute__((ext_vector_type(4)));
typedef float f32x2 __attribute__((ext_vector_type(2)));

// f32 -> bf16 round-to-nearest-even
static __device__ __forceinline__ ushort_t f2bf(float f) {
    uint_t u = __float_as_uint(f);
    uint_t r = (u + 0x7FFFu + ((u >> 16) & 1u)) >> 16;
    return (ushort_t)r;
}

// ---------------------------------------------------------------------------
// Kernel A: Mt[col][f] = bf16( sum_e (att[r,0]*basis[0,f,e]+att[r,1]*basis[1,f,e]) * fc_w[e,o] )
// ---------------------------------------------------------------------------
__global__ __launch_bounds__(256) void k_make_M(const float* __restrict__ att,
                                                const float* __restrict__ basis,
                                                const float* __restrict__ fcw,
                                                ushort_t* __restrict__ Mt) {
    int tid = blockIdx.x * 256 + threadIdx.x;
    if (tid >= RR * FF * OUTD) return;
    int r = tid / (FF * OUTD);
    int rem = tid - r * FF * OUTD;
    int f = rem >> 6;
    int o = rem & 63;
    float a0 = att[r * 2 + 0], a1 = att[r * 2 + 1];
    const float* b0 = basis + f * EFFD;
    const float* b1 = basis + FF * EFFD + f * EFFD;
    float acc = 0.f;
#pragma unroll 4
    for (int e = 0; e < EFFD; ++e) {
        float w = a0 * b0[e] + a1 * b1[e];
        acc += w * fcw[e * OUTD + o];
    }
    Mt[(size_t)(r * OUTD + o) * FF + f] = f2bf(acc);
}

// ---------------------------------------------------------------------------
// Merged Pass 1: part-blocks (bid < PART_BLOCKS) bucket the edges;
// gemm-blocks compute g = bf16((feat @ M) * cj). B-fragments are read
// DIRECTLY FROM GLOBAL (Mt slice = 40 KB, L2-resident, shared by all
// blocks) -> no mtS in LDS: union shrinks to 29.7 KB (5 blocks/CU) and
// the 40 bank-conflicted ds_reads/thread disappear.
// ---------------------------------------------------------------------------
union SharedPG {
    struct {
        ushort_t featS[64][136];           // 17.4 KB
    } g;
    struct {
        uint_t stage0[CHUNKE];
        uint_t stage1[CHUNKE];
        int cnt[2 * NBKT];
        int cur[2 * NBKT];
        int gpos[2 * NBKT];
    } p;                                   // 29.7 KB
};

__global__ __launch_bounds__(256) void k_pg(const int* __restrict__ ed,
                                            const int* __restrict__ ei,
                                            int* __restrict__ tails,
                                            uint_t* __restrict__ coarse,
                                            const float* __restrict__ featA,
                                            const float* __restrict__ cjA,
                                            const float* __restrict__ featB,
                                            const float* __restrict__ cjB,
                                            const ushort_t* __restrict__ Mt,
                                            ushort_t* __restrict__ gA,
                                            ushort_t* __restrict__ gB) {
    __shared__ SharedPG sh;
    const int bid = blockIdx.x;
    const int t = threadIdx.x;

    if (bid < PART_BLOCKS) {
        // ---------------- coarse partition (both dirs per block) -----------
        int chunk = bid & (NCHUNKE - 1);
        int r = bid >> 7;
        const int* A = ed + (size_t)r * EE;   // drug endpoints
        const int* B = ei + (size_t)r * EE;   // disease endpoints
        int* tl0 = tails + (0 * RR + r) * NBKT;
        int* tl1 = tails + (1 * RR + r) * NBKT;
        uint_t* cb0 = coarse + (size_t)(0 * RR + r) * NBKT * CAP;
        uint_t* cb1 = coarse + (size_t)(1 * RR + r) * NBKT * CAP;

        for (int u = t; u < 2 * NBKT; u += 256) { sh.p.cnt[u] = 0; sh.p.cur[u] = 0; }
        __syncthreads();

        int e0 = chunk * CHUNKE;
        for (int i = t; i < CHUNKE; i += 256) {
            int a = __builtin_nontemporal_load(A + e0 + i);
            int b = __builtin_nontemporal_load(B + e0 + i);
            sh.p.stage0[i] = ((uint_t)(b >> 8) << 24) | ((uint_t)(b & 255) << 16) | (uint_t)(ushort_t)a;
            sh.p.stage1[i] = ((uint_t)(a >> 8) << 24) | ((uint_t)(a & 255) << 16) | (uint_t)(ushort_t)b;
            atomicAdd(&sh.p.cnt[b >> 8], 1);
            atomicAdd(&sh.p.cnt[NBKT + (a >> 8)], 1);
        }
        __syncthreads();

        for (int u = t; u < 2 * NBKT; u += 256) {
            int* tl = (u < NBKT) ? tl0 : tl1;
            int bb = (u < NBKT) ? u : u - NBKT;
            sh.p.gpos[u] = atomicAdd(&tl[bb], sh.p.cnt[u]);
        }
        __syncthreads();

        for (int i = t; i < CHUNKE; i += 256) {
            uint_t e = sh.p.stage0[i];
            int b = e >> 24;
            int q = atomicAdd(&sh.p.cur[b], 1);
            int idx = sh.p.gpos[b] + q;
            if (idx < CAP)
                cb0[(size_t)b * CAP + idx] = e & 0x00FFFFFFu;
        }
        for (int i = t; i < CHUNKE; i += 256) {
            uint_t e = sh.p.stage1[i];
            int b = e >> 24;
            int q = atomicAdd(&sh.p.cur[NBKT + b], 1);
            int idx = sh.p.gpos[NBKT + b] + q;
            if (idx < CAP)
                cb1[(size_t)b * CAP + idx] = e & 0x00FFFFFFu;
        }
        return;
    }

    // ---------------- MFMA transform g[r][n][o] -----------------------------
    int gid = bid - PART_BLOCKS;
    int bx = gid % GEMM_RB;
    int qq = gid / GEMM_RB;          // 0..3
    int by = qq & 1;                 // col-half
    int bz = qq >> 1;                // side

    const float* feat; const float* cj; ushort_t* g;
    if (bz == 0) { feat = featA; cj = cjA; g = gA; }
    else         { feat = featB; cj = cjB; g = gB; }

    const int row0 = bx * 64;
    const int ch0  = by * 160;

    for (int i = t; i < 64 * 32; i += 256) {
        int r  = i >> 5;
        int c4 = (i & 31) << 2;
        float4 v = make_float4(0.f, 0.f, 0.f, 0.f);
        int row = row0 + r;
        if (row < NDRUG) v = *(const float4*)(feat + (size_t)row * FF + c4);
        ushort4 pk;
        pk.x = f2bf(v.x); pk.y = f2bf(v.y); pk.z = f2bf(v.z); pk.w = f2bf(v.w);
        *(ushort4*)&sh.g.featS[r][c4] = pk;
    }
    __syncthreads();

    const int w = t >> 6;
    const int l = t & 63;
    const int lr = l & 15;
    const int lg = l >> 4;

    short8 afrag[4];
#pragma unroll
    for (int ks = 0; ks < 4; ++ks)
        afrag[ks] = *(const short8*)&sh.g.featS[w * 16 + lr][ks * 32 + lg * 8];

    const int rbase = row0 + w * 16 + (lg << 2);
    float cjv[4];
#pragma unroll
    for (int rg = 0; rg < 4; ++rg)
        cjv[rg] = (rbase + rg < NDRUG) ? cj[rbase + rg] : 0.f;

    // per-lane Mt base: col = ch0 + n*16 + lr, f-offset = ks*32 + lg*8
    const ushort_t* mtb = Mt + (size_t)(ch0 + lr) * FF + lg * 8;

#pragma unroll
    for (int n = 0; n < 10; ++n) {
        f32x4 c = {0.f, 0.f, 0.f, 0.f};
#pragma unroll
        for (int ks = 0; ks < 4; ++ks) {
            short8 b = *(const short8*)(mtb + (size_t)n * 16 * FF + ks * 32);
            c = __builtin_amdgcn_mfma_f32_16x16x32_bf16(afrag[ks], b, c, 0, 0, 0);
        }
        int col = ch0 + n * 16 + lr;
        int rr  = col >> 6;
        int oo  = col & 63;
#pragma unroll
        for (int rg = 0; rg < 4; ++rg) {
            int row = rbase + rg;
            if (row < NDRUG)
                g[((size_t)rr * NDRUG + row) * OUTD + oo] = f2bf(c[rg] * cjv[rg]);
        }
    }
}

// ---------------------------------------------------------------------------
// Pass 2 (merged fine-sort + aggregation): one block per coarse bucket.
// XCD-contiguous bucket remap. Bucket entries register-staged (one NT read);
// LDS counting sort; 4 waves x 64 bins, 16-lane uint2 gathers, packed f32x2
// accumulate, quarter shfl_xor reduce, fused ci+bias NT f32x4 store.
// ---------------------------------------------------------------------------
__global__ __launch_bounds__(256) void k_fuse(const ushort_t* __restrict__ gd,
                                              const ushort_t* __restrict__ gi,
                                              const int* __restrict__ tails,
                                              const uint_t* __restrict__ coarse,
                                              const float* __restrict__ ci_drug,
                                              const float* __restrict__ ci_dis,
                                              const float* __restrict__ fcb,
                                              float* __restrict__ out_drug,
                                              float* __restrict__ out_dis) {
    int bid = blockIdx.x;
    int gb = (bid & 7) * (NGB / 8) + (bid >> 3);   // XCD-contiguous range
    int dir = gb / (RR * NBKT);
    int rem = gb - dir * (RR * NBKT);
    int r = rem / NBKT;
    int b = rem - r * NBKT;

    const ushort_t* g = dir ? gi : gd;
    const float* ci   = dir ? ci_drug : ci_dis;
    float* outp       = dir ? out_drug : out_dis;

    const uint_t* cb = coarse + (size_t)gb * CAP;
    int count = tails[gb]; if (count > CAP) count = CAP;

    __shared__ ushort_t lsorted[CAP];   // 8 KB
    __shared__ int hist[256];
    __shared__ int incl[256];
    __shared__ int cur[256];

    int t = threadIdx.x;

    // register-stage the bucket: one NT read of coarse
    uint_t ereg[16];
#pragma unroll
    for (int k = 0; k < 16; ++k) {
        int i = k * 256 + t;
        ereg[k] = (i < count) ? __builtin_nontemporal_load(cb + i) : 0xFFFFFFFFu;
    }

    hist[t] = 0;
    __syncthreads();
#pragma unroll
    for (int k = 0; k < 16; ++k)
        if (ereg[k] != 0xFFFFFFFFu)
            atomicAdd(&hist[(ereg[k] >> 16) & 255], 1);
    __syncthreads();

    int v = hist[t];
    incl[t] = v;
    __syncthreads();
    for (int off = 1; off < 256; off <<= 1) {
        int x = (t >= off) ? incl[t - off] : 0;
        __syncthreads();
        incl[t] += x;
        __syncthreads();
    }
    cur[t] = incl[t] - v;
    __syncthreads();

#pragma unroll
    for (int k = 0; k < 16; ++k) {
        uint_t e = ereg[k];
        if (e != 0xFFFFFFFFu) {
            int p = atomicAdd(&cur[(e >> 16) & 255], 1);
            lsorted[p] = (ushort_t)e;
        }
    }
    __syncthreads();

    // aggregation: wave w -> bins w*64 .. w*64+63
    const int w       = t >> 6;
    const int lane    = t & 63;
    const int quarter = lane >> 4;
    const int q       = lane & 15;
    const ushort_t* grow = g + (size_t)r * NDRUG * OUTD + q * 4;
    const float4 bb = *(const float4*)(fcb + q * 4);

    for (int ib = 0; ib < 64; ++ib) {
        int dstlow = w * 64 + ib;
        int dst = b * 256 + dstlow;
        if (dst >= NDIS) break;
        int start = dstlow ? incl[dstlow - 1] : 0;
        int end = incl[dstlow];

        f32x2 a01 = {0.f, 0.f}, a23 = {0.f, 0.f};
        for (int j = start; j < end; j += 8) {
            uint2 u[2];
#pragma unroll
            for (int k = 0; k < 2; ++k) {
                int jj = j + 4 * k + quarter;
                int cl = jj < end ? jj : j;
                int sj = (int)lsorted[cl];
                u[k] = *(const uint2*)(grow + (size_t)sj * OUTD);
            }
#pragma unroll
            for (int k = 0; k < 2; ++k) {
                int jj = j + 4 * k + quarter;
                uint_t ux = jj < end ? u[k].x : 0u;
                uint_t uy = jj < end ? u[k].y : 0u;
                f32x2 p0 = { __uint_as_float(ux << 16), __uint_as_float(ux & 0xffff0000u) };
                f32x2 p1 = { __uint_as_float(uy << 16), __uint_as_float(uy & 0xffff0000u) };
                a01 += p0;
                a23 += p1;
            }
        }
        float a0 = a01.x, a1 = a01.y, a2 = a23.x, a3 = a23.y;
        a0 += __shfl_xor(a0, 16); a1 += __shfl_xor(a1, 16);
        a2 += __shfl_xor(a2, 16); a3 += __shfl_xor(a3, 16);
        a0 += __shfl_xor(a0, 32); a1 += __shfl_xor(a1, 32);
        a2 += __shfl_xor(a2, 32); a3 += __shfl_xor(a3, 32);
        if (quarter == 0) {
            float civ = ci[dst];
            f32x4 o;
            o.x = a0 * civ + bb.x;
            o.y = a1 * civ + bb.y;
            o.z = a2 * civ + bb.z;
            o.w = a3 * civ + bb.w;
            __builtin_nontemporal_store(o,
                (f32x4*)(outp + (size_t)dst * NCOL + r * OUTD + q * 4));
        }
    }
}

// ---------------------------------------------------------------------------
extern "C" void kernel_launch(void* const* d_in, const int* in_sizes, int n_in,
                              void* d_out, int out_size, void* d_ws, size_t ws_size,
                              hipStream_t stream) {
    const float* drug_feat = (const float*)d_in[0];
    const float* dis_feat  = (const float*)d_in[1];
    const float* cj_drug   = (const float*)d_in[2];
    const float* ci_drug   = (const float*)d_in[3];
    const float* cj_dis    = (const float*)d_in[4];
    const float* ci_dis    = (const float*)d_in[5];
    const float* att       = (const float*)d_in[6];
    const float* basis     = (const float*)d_in[7];
    const float* fcw       = (const float*)d_in[8];
    const float* fcb       = (const float*)d_in[9];
    const int*   edge_drug = (const int*)d_in[10];
    const int*   edge_dis  = (const int*)d_in[11];

    float* out      = (float*)d_out;
    float* out_drug = out;
    float* out_dis  = out + (size_t)NDRUG * NCOL;

    // Workspace layout (~98.3 MB):
    //   gd (bf16, [R][N][64])   32,000,000 @ 0
    //   gi (bf16, [R][N][64])   32,000,000 @ 32,000,000
    //   Mt (bf16)      163,840 @ 64,000,000
    //   tails (int)      7,840 @ 66,200,000
    //   coarse (u32) 32,112,640 @ 66,208,000
    char* ws = (char*)d_ws;
    ushort_t* gd      = (ushort_t*)ws;
    ushort_t* gi      = (ushort_t*)(ws + 32000000);
    ushort_t* Mtb     = (ushort_t*)(ws + 64000000);
    int*      tails   = (int*)(ws + 66200000);
    uint_t*   coarse  = (uint_t*)(ws + 66208000);

    // zero bucket tails
    hipMemsetAsync(tails, 0, NGB * sizeof(int), stream);

    // A: fused att*basis*fc_w -> Mt bf16 [320][128]
    k_make_M<<<dim3((RR * FF * OUTD + 255) / 256), 256, 0, stream>>>(att, basis, fcw, Mtb);

    // Merged: coarse partition (blocks 0..639) + MFMA transform (rest)
    k_pg<<<dim3(PG_BLOCKS), 256, 0, stream>>>(edge_drug, edge_dis, tails, coarse,
                                              drug_feat, cj_drug, dis_feat, cj_dis,
                                              Mtb, gd, gi);

    // Merged fine-sort + gather aggregation + fused ci-scale + bias
    k_fuse<<<dim3(NGB), 256, 0, stream>>>(gd, gi, tails, coarse,
                                          ci_drug, ci_dis, fcb,
                                          out_drug, out_dis);
}

// Round 19
// 202.602 us; speedup vs baseline: 1.7188x; 1.0047x over previous
//
#include <hip/hip_runtime.h>

// Problem constants
#define NDRUG 50000
#define NDIS  50000
#define RR    5
#define FF    128
#define EFFD  128
#define OUTD  64
#define EE    400000
#define NCOL  (RR * OUTD)        // 320 columns in fused OUTPUT layout [n][r*64+o]
#define NEDGE (RR * EE)          // 2,000,000 edges per direction

#define NROWP 50016              // padded rows per rating region (rows 50000..50015 are ZERO)

// Two-level bucket sort
#define NBKT    196              // coarse buckets per (dir,r): dst>>8 (50000/256)
#define CAP     4096             // slot capacity per bucket
#define NGB     (2 * RR * NBKT)  // 1960 global buckets

#define NCHUNKE 128              // edge chunks per r (both dirs handled per block)
#define CHUNKE  (EE / NCHUNKE)   // 3125 edges per chunk (exact)

// merged part+gemm dispatch geometry
#define PART_BLOCKS (NCHUNKE * RR)            // 640
#define GEMM_RB     ((NDRUG + 63) / 64)       // 782 row-blocks
#define GEMM_BLOCKS (GEMM_RB * 4)             // x2 col-half x2 side = 3128
#define PG_BLOCKS   (PART_BLOCKS + GEMM_BLOCKS)

typedef unsigned short ushort_t;
typedef unsigned int uint_t;
typedef short short8 __attribute__((ext_vector_type(8)));
typedef float f32x4 __attribute__((ext_vector_type(4)));
typedef float f32x2 __attribute__((ext_vector_type(2)));

// f32 -> bf16 round-to-nearest-even
static __device__ __forceinline__ ushort_t f2bf(float f) {
    uint_t u = __float_as_uint(f);
    uint_t r = (u + 0x7FFFu + ((u >> 16) & 1u)) >> 16;
    return (ushort_t)r;
}

// ---------------------------------------------------------------------------
// Kernel A: Mt[col][f] = bf16( sum_e (att[r,0]*basis[0,f,e]+att[r,1]*basis[1,f,e]) * fc_w[e,o] )
// ---------------------------------------------------------------------------
__global__ __launch_bounds__(256) void k_make_M(const float* __restrict__ att,
                                                const float* __restrict__ basis,
                                                const float* __restrict__ fcw,
                                                ushort_t* __restrict__ Mt) {
    int tid = blockIdx.x * 256 + threadIdx.x;
    if (tid >= RR * FF * OUTD) return;
    int r = tid / (FF * OUTD);
    int rem = tid - r * FF * OUTD;
    int f = rem >> 6;
    int o = rem & 63;
    float a0 = att[r * 2 + 0], a1 = att[r * 2 + 1];
    const float* b0 = basis + f * EFFD;
    const float* b1 = basis + FF * EFFD + f * EFFD;
    float acc = 0.f;
#pragma unroll 4
    for (int e = 0; e < EFFD; ++e) {
        float w = a0 * b0[e] + a1 * b1[e];
        acc += w * fcw[e * OUTD + o];
    }
    Mt[(size_t)(r * OUTD + o) * FF + f] = f2bf(acc);
}

// ---------------------------------------------------------------------------
// Merged Pass 1: part-blocks (bid < PART_BLOCKS) bucket the edges (blocks
// 0..9 additionally zero the 16 pad rows of one (array, r) region);
// gemm-blocks compute g = bf16((feat @ M) * cj) with B-fragments read
// directly from the L2-resident Mt.
// ---------------------------------------------------------------------------
union SharedPG {
    struct {
        ushort_t featS[64][136];           // 17.4 KB
    } g;
    struct {
        uint_t stage0[CHUNKE];
        uint_t stage1[CHUNKE];
        int cnt[2 * NBKT];
        int cur[2 * NBKT];
        int gpos[2 * NBKT];
    } p;                                   // 29.7 KB
};

__global__ __launch_bounds__(256) void k_pg(const int* __restrict__ ed,
                                            const int* __restrict__ ei,
                                            int* __restrict__ tails,
                                            uint_t* __restrict__ coarse,
                                            const float* __restrict__ featA,
                                            const float* __restrict__ cjA,
                                            const float* __restrict__ featB,
                                            const float* __restrict__ cjB,
                                            const ushort_t* __restrict__ Mt,
                                            ushort_t* __restrict__ gA,
                                            ushort_t* __restrict__ gB) {
    __shared__ SharedPG sh;
    const int bid = blockIdx.x;
    const int t = threadIdx.x;

    if (bid < PART_BLOCKS) {
        // blocks 0..9: zero the pad rows (rows 50000..50015) of one region
        if (bid < 2 * RR) {
            ushort_t* garr = (bid & 1) ? gB : gA;
            int r = bid >> 1;
            uint_t* z = (uint_t*)(garr + ((size_t)r * NROWP + NDRUG) * OUTD);
            // 16 rows x 64 u16 = 512 uints
            for (int i = t; i < 512; i += 256) z[i] = 0u;
        }

        // ---------------- coarse partition (both dirs per block) -----------
        int chunk = bid & (NCHUNKE - 1);
        int r = bid >> 7;
        const int* A = ed + (size_t)r * EE;   // drug endpoints
        const int* B = ei + (size_t)r * EE;   // disease endpoints
        int* tl0 = tails + (0 * RR + r) * NBKT;
        int* tl1 = tails + (1 * RR + r) * NBKT;
        uint_t* cb0 = coarse + (size_t)(0 * RR + r) * NBKT * CAP;
        uint_t* cb1 = coarse + (size_t)(1 * RR + r) * NBKT * CAP;

        for (int u = t; u < 2 * NBKT; u += 256) { sh.p.cnt[u] = 0; sh.p.cur[u] = 0; }
        __syncthreads();

        int e0 = chunk * CHUNKE;
        for (int i = t; i < CHUNKE; i += 256) {
            int a = __builtin_nontemporal_load(A + e0 + i);
            int b = __builtin_nontemporal_load(B + e0 + i);
            sh.p.stage0[i] = ((uint_t)(b >> 8) << 24) | ((uint_t)(b & 255) << 16) | (uint_t)(ushort_t)a;
            sh.p.stage1[i] = ((uint_t)(a >> 8) << 24) | ((uint_t)(a & 255) << 16) | (uint_t)(ushort_t)b;
            atomicAdd(&sh.p.cnt[b >> 8], 1);
            atomicAdd(&sh.p.cnt[NBKT + (a >> 8)], 1);
        }
        __syncthreads();

        for (int u = t; u < 2 * NBKT; u += 256) {
            int* tl = (u < NBKT) ? tl0 : tl1;
            int bb = (u < NBKT) ? u : u - NBKT;
            sh.p.gpos[u] = atomicAdd(&tl[bb], sh.p.cnt[u]);
        }
        __syncthreads();

        for (int i = t; i < CHUNKE; i += 256) {
            uint_t e = sh.p.stage0[i];
            int b = e >> 24;
            int q = atomicAdd(&sh.p.cur[b], 1);
            int idx = sh.p.gpos[b] + q;
            if (idx < CAP)
                cb0[(size_t)b * CAP + idx] = e & 0x00FFFFFFu;
        }
        for (int i = t; i < CHUNKE; i += 256) {
            uint_t e = sh.p.stage1[i];
            int b = e >> 24;
            int q = atomicAdd(&sh.p.cur[NBKT + b], 1);
            int idx = sh.p.gpos[NBKT + b] + q;
            if (idx < CAP)
                cb1[(size_t)b * CAP + idx] = e & 0x00FFFFFFu;
        }
        return;
    }

    // ---------------- MFMA transform g[r][n][o] -----------------------------
    int gid = bid - PART_BLOCKS;
    int bx = gid % GEMM_RB;
    int qq = gid / GEMM_RB;          // 0..3
    int by = qq & 1;                 // col-half
    int bz = qq >> 1;                // side

    const float* feat; const float* cj; ushort_t* g;
    if (bz == 0) { feat = featA; cj = cjA; g = gA; }
    else         { feat = featB; cj = cjB; g = gB; }

    const int row0 = bx * 64;
    const int ch0  = by * 160;

    for (int i = t; i < 64 * 32; i += 256) {
        int r  = i >> 5;
        int c4 = (i & 31) << 2;
        float4 v = make_float4(0.f, 0.f, 0.f, 0.f);
        int row = row0 + r;
        if (row < NDRUG) v = *(const float4*)(feat + (size_t)row * FF + c4);
        ushort4 pk;
        pk.x = f2bf(v.x); pk.y = f2bf(v.y); pk.z = f2bf(v.z); pk.w = f2bf(v.w);
        *(ushort4*)&sh.g.featS[r][c4] = pk;
    }
    __syncthreads();

    const int w = t >> 6;
    const int l = t & 63;
    const int lr = l & 15;
    const int lg = l >> 4;

    short8 afrag[4];
#pragma unroll
    for (int ks = 0; ks < 4; ++ks)
        afrag[ks] = *(const short8*)&sh.g.featS[w * 16 + lr][ks * 32 + lg * 8];

    const int rbase = row0 + w * 16 + (lg << 2);
    float cjv[4];
#pragma unroll
    for (int rg = 0; rg < 4; ++rg)
        cjv[rg] = (rbase + rg < NDRUG) ? cj[rbase + rg] : 0.f;

    // per-lane Mt base: col = ch0 + n*16 + lr, f-offset = ks*32 + lg*8
    const ushort_t* mtb = Mt + (size_t)(ch0 + lr) * FF + lg * 8;

#pragma unroll
    for (int n = 0; n < 10; ++n) {
        f32x4 c = {0.f, 0.f, 0.f, 0.f};
#pragma unroll
        for (int ks = 0; ks < 4; ++ks) {
            short8 b = *(const short8*)(mtb + (size_t)n * 16 * FF + ks * 32);
            c = __builtin_amdgcn_mfma_f32_16x16x32_bf16(afrag[ks], b, c, 0, 0, 0);
        }
        int col = ch0 + n * 16 + lr;
        int rr  = col >> 6;
        int oo  = col & 63;
#pragma unroll
        for (int rg = 0; rg < 4; ++rg) {
            int row = rbase + rg;
            if (row < NDRUG)
                g[((size_t)rr * NROWP + row) * OUTD + oo] = f2bf(c[rg] * cjv[rg]);
        }
    }
}

// ---------------------------------------------------------------------------
// Pass 2 (merged fine-sort + aggregation): one block per coarse bucket.
// Bins are PADDED to a multiple of 8 in the LDS counting sort; pad entries
// carry sentinel src=NDRUG (a zeroed pad row) -> the aggregation inner loop
// is completely predication-free.
// ---------------------------------------------------------------------------
__global__ __launch_bounds__(256) void k_fuse(const ushort_t* __restrict__ gd,
                                              const ushort_t* __restrict__ gi,
                                              const int* __restrict__ tails,
                                              const uint_t* __restrict__ coarse,
                                              const float* __restrict__ ci_drug,
                                              const float* __restrict__ ci_dis,
                                              const float* __restrict__ fcb,
                                              float* __restrict__ out_drug,
                                              float* __restrict__ out_dis) {
    int bid = blockIdx.x;
    int gb = (bid & 7) * (NGB / 8) + (bid >> 3);   // XCD-contiguous range
    int dir = gb / (RR * NBKT);
    int rem = gb - dir * (RR * NBKT);
    int r = rem / NBKT;
    int b = rem - r * NBKT;

    const ushort_t* g = dir ? gi : gd;
    const float* ci   = dir ? ci_drug : ci_dis;
    float* outp       = dir ? out_drug : out_dis;

    const uint_t* cb = coarse + (size_t)gb * CAP;
    int count = tails[gb]; if (count > CAP) count = CAP;

    __shared__ ushort_t lsorted[CAP];   // 8 KB
    __shared__ int hist[256];
    __shared__ int incl[256];           // padded inclusive scan
    __shared__ int cur[256];

    int t = threadIdx.x;

    // register-stage the bucket: one NT read of coarse
    uint_t ereg[16];
#pragma unroll
    for (int k = 0; k < 16; ++k) {
        int i = k * 256 + t;
        ereg[k] = (i < count) ? __builtin_nontemporal_load(cb + i) : 0xFFFFFFFFu;
    }

    hist[t] = 0;
    __syncthreads();
#pragma unroll
    for (int k = 0; k < 16; ++k)
        if (ereg[k] != 0xFFFFFFFFu)
            atomicAdd(&hist[(ereg[k] >> 16) & 255], 1);
    __syncthreads();

    int v = hist[t];
    int p = (v + 7) & ~7;              // bin padded to multiple of 8
    incl[t] = p;
    __syncthreads();
    for (int off = 1; off < 256; off <<= 1) {
        int x = (t >= off) ? incl[t - off] : 0;
        __syncthreads();
        incl[t] += x;
        __syncthreads();
    }
    cur[t] = incl[t] - p;              // padded exclusive start
    __syncthreads();

#pragma unroll
    for (int k = 0; k < 16; ++k) {
        uint_t e = ereg[k];
        if (e != 0xFFFFFFFFu) {
            int pos = atomicAdd(&cur[(e >> 16) & 255], 1);
            if (pos < CAP) lsorted[pos] = (ushort_t)e;
        }
    }
    __syncthreads();

    // fill each bin's pad slots with the zero-row sentinel
    {
        int fe = incl[t]; if (fe > CAP) fe = CAP;
        for (int i = cur[t]; i < fe; ++i) lsorted[i] = (ushort_t)NDRUG;
    }
    __syncthreads();

    // aggregation: wave w -> bins w*64 .. w*64+63 (predication-free)
    const int w       = t >> 6;
    const int lane    = t & 63;
    const int quarter = lane >> 4;
    const int q       = lane & 15;
    const ushort_t* grow = g + (size_t)r * NROWP * OUTD + q * 4;
    const float4 bb = *(const float4*)(fcb + q * 4);

    for (int ib = 0; ib < 64; ++ib) {
        int dstlow = w * 64 + ib;
        int dst = b * 256 + dstlow;
        if (dst >= NDIS) break;
        int start = dstlow ? incl[dstlow - 1] : 0;
        int end = incl[dstlow];
        if (start > CAP) start = CAP;
        if (end > CAP) end = CAP;

        f32x2 a01 = {0.f, 0.f}, a23 = {0.f, 0.f};
        for (int j = start; j < end; j += 8) {
            int s0 = (int)lsorted[j + quarter];
            int s1 = (int)lsorted[j + 4 + quarter];
            uint2 u0 = *(const uint2*)(grow + (size_t)s0 * OUTD);
            uint2 u1 = *(const uint2*)(grow + (size_t)s1 * OUTD);
            f32x2 p0 = { __uint_as_float(u0.x << 16), __uint_as_float(u0.x & 0xffff0000u) };
            f32x2 p1 = { __uint_as_float(u0.y << 16), __uint_as_float(u0.y & 0xffff0000u) };
            f32x2 p2 = { __uint_as_float(u1.x << 16), __uint_as_float(u1.x & 0xffff0000u) };
            f32x2 p3 = { __uint_as_float(u1.y << 16), __uint_as_float(u1.y & 0xffff0000u) };
            a01 += p0; a23 += p1;
            a01 += p2; a23 += p3;
        }
        float a0 = a01.x, a1 = a01.y, a2 = a23.x, a3 = a23.y;
        a0 += __shfl_xor(a0, 16); a1 += __shfl_xor(a1, 16);
        a2 += __shfl_xor(a2, 16); a3 += __shfl_xor(a3, 16);
        a0 += __shfl_xor(a0, 32); a1 += __shfl_xor(a1, 32);
        a2 += __shfl_xor(a2, 32); a3 += __shfl_xor(a3, 32);
        if (quarter == 0) {
            float civ = ci[dst];
            f32x4 o;
            o.x = a0 * civ + bb.x;
            o.y = a1 * civ + bb.y;
            o.z = a2 * civ + bb.z;
            o.w = a3 * civ + bb.w;
            __builtin_nontemporal_store(o,
                (f32x4*)(outp + (size_t)dst * NCOL + r * OUTD + q * 4));
        }
    }
}

// ---------------------------------------------------------------------------
extern "C" void kernel_launch(void* const* d_in, const int* in_sizes, int n_in,
                              void* d_out, int out_size, void* d_ws, size_t ws_size,
                              hipStream_t stream) {
    const float* drug_feat = (const float*)d_in[0];
    const float* dis_feat  = (const float*)d_in[1];
    const float* cj_drug   = (const float*)d_in[2];
    const float* ci_drug   = (const float*)d_in[3];
    const float* cj_dis    = (const float*)d_in[4];
    const float* ci_dis    = (const float*)d_in[5];
    const float* att       = (const float*)d_in[6];
    const float* basis     = (const float*)d_in[7];
    const float* fcw       = (const float*)d_in[8];
    const float* fcb       = (const float*)d_in[9];
    const int*   edge_drug = (const int*)d_in[10];
    const int*   edge_dis  = (const int*)d_in[11];

    float* out      = (float*)d_out;
    float* out_drug = out;
    float* out_dis  = out + (size_t)NDRUG * NCOL;

    // Workspace layout (~96.3 MB):
    //   gd (bf16, [R][50016][64])  32,010,240 @ 0
    //   gi (bf16, [R][50016][64])  32,010,240 @ 32,010,240
    //   Mt (bf16)          163,840 @ 64,020,480
    //   tails (int)          7,840 @ 64,184,320
    //   coarse (u32)    32,112,640 @ 64,192,160
    char* ws = (char*)d_ws;
    ushort_t* gd      = (ushort_t*)ws;
    ushort_t* gi      = (ushort_t*)(ws + 32010240);
    ushort_t* Mtb     = (ushort_t*)(ws + 64020480);
    int*      tails   = (int*)(ws + 64184320);
    uint_t*   coarse  = (uint_t*)(ws + 64192160);

    // zero bucket tails
    hipMemsetAsync(tails, 0, NGB * sizeof(int), stream);

    // A: fused att*basis*fc_w -> Mt bf16 [320][128]
    k_make_M<<<dim3((RR * FF * OUTD + 255) / 256), 256, 0, stream>>>(att, basis, fcw, Mtb);

    // Merged: coarse partition + pad-row zeroing (blocks 0..639) + MFMA transform
    k_pg<<<dim3(PG_BLOCKS), 256, 0, stream>>>(edge_drug, edge_dis, tails, coarse,
                                              drug_feat, cj_drug, dis_feat, cj_dis,
                                              Mtb, gd, gi);

    // Merged fine-sort + gather aggregation + fused ci-scale + bias
    k_fuse<<<dim3(NGB), 256, 0, stream>>>(gd, gi, tails, coarse,
                                          ci_drug, ci_dis, fcb,
                                          out_drug, out_dis);
}